// Round 1
// baseline (1198.809 us; speedup 1.0000x reference)
//
#include <hip/hip_runtime.h>
#include <hip/hip_bf16.h>
#include <cstdint>

#define L_SEQ   2048
#define BATCH   2
#define ROWS    (BATCH*L_SEQ)     // 4096
#define DMODEL  1024
#define DINNER  2048
#define DSTATE  128
#define NHEADS  32
#define DIN_PROJ 4384
#define DIN_PAD  4480             // padded to multiple of 128 for BN tiles
#define CONVDIM  2304
#define DMLP    4096

typedef __attribute__((ext_vector_type(4))) float f32x4;
typedef __attribute__((ext_vector_type(8))) short bf16x8;

static __device__ __forceinline__ short f2bf(float f) {
  union { float f; unsigned int i; } v; v.f = f;
  unsigned int r = v.i + 0x7fffu + ((v.i >> 16) & 1u);  // round-to-nearest-even
  return (short)(r >> 16);
}

static __device__ __forceinline__ void gl2lds16(const void* g, void* l) {
  __builtin_amdgcn_global_load_lds((const __attribute__((address_space(1))) void*)g,
                                   (__attribute__((address_space(3))) void*)l, 16, 0, 0);
}

// ---------------- fp32 -> bf16 weight convert with row padding ----------------
__global__ void cvt_pad_kernel(const float* __restrict__ src, short* __restrict__ dst,
                               long rows_src, long total, long K)
{
  long i = (long)blockIdx.x * 256 + threadIdx.x;
  long stride = (long)gridDim.x * 256;
  for (; i < total; i += stride) {
    long r = i / K;
    dst[i] = (r < rows_src) ? f2bf(src[i]) : (short)0;
  }
}

// ---------------- L2-style norm: w * x * rsqrt(sum(x^2) + 1e-6), D=1024 -> bf16 ----------------
__global__ __launch_bounds__(256) void rmsnorm_l2_kernel(const float* __restrict__ in,
                                                         const float* __restrict__ w,
                                                         short* __restrict__ out)
{
  int row = blockIdx.x, tid = threadIdx.x;
  const float* xr = in + (long)row * DMODEL;
  float v[4]; float s = 0.f;
  #pragma unroll
  for (int i = 0; i < 4; i++) { v[i] = xr[tid + i*256]; s += v[i]*v[i]; }
  for (int o = 32; o; o >>= 1) s += __shfl_down(s, o);
  __shared__ float red[4];
  if ((tid & 63) == 0) red[tid >> 6] = s;
  __syncthreads();
  float tot = red[0] + red[1] + red[2] + red[3];
  float sc = rsqrtf(tot + 1e-6f);
  #pragma unroll
  for (int i = 0; i < 4; i++) {
    int c = tid + i*256;
    out[(long)row*DMODEL + c] = f2bf(v[i] * sc * w[c]);
  }
}

// ---------------- bf16 GEMM: C[M,N] = A[M,K] @ W[N,K]^T, 128x128 tile, BK=64 ----------------
// EPI: 0 = store f32; 1 = +resid f32; 2 = gelu(C+bias) -> bf16; 3 = C+bias+resid -> f32
template<int EPI>
__global__ __launch_bounds__(256)
void gemm_bt_kernel(const short* __restrict__ A, const short* __restrict__ W,
                    const float* __restrict__ bias, const float* __restrict__ resid,
                    void* __restrict__ out, int N, int K)
{
  __shared__ short As[128*64];
  __shared__ short Ws[128*64];
  const int tid = threadIdx.x;
  const int lane = tid & 63, wid = tid >> 6;
  const int wm = wid >> 1, wn = wid & 1;
  const long arow0 = (long)blockIdx.x * 128;
  const long wrow0 = (long)blockIdx.y * 128;
  const int srow = tid >> 3, scol = (tid & 7) * 8;

  f32x4 acc[4][4];
  #pragma unroll
  for (int m = 0; m < 4; m++)
    #pragma unroll
    for (int n = 0; n < 4; n++)
      #pragma unroll
      for (int j = 0; j < 4; j++) acc[m][n][j] = 0.f;

  for (int kt = 0; kt < K; kt += 64) {
    #pragma unroll
    for (int i = 0; i < 4; i++) {
      const short* g = A + (arow0 + i*32 + srow) * (long)K + kt + scol;
      gl2lds16(g, &As[(i*32 + srow)*64 + scol]);
    }
    #pragma unroll
    for (int i = 0; i < 4; i++) {
      const short* g = W + (wrow0 + i*32 + srow) * (long)K + kt + scol;
      gl2lds16(g, &Ws[(i*32 + srow)*64 + scol]);
    }
    __syncthreads();   // compiler emits vmcnt(0) drain before barrier
    #pragma unroll
    for (int kk = 0; kk < 64; kk += 32) {
      bf16x8 a[4], b[4];
      const int ko = kk + (lane >> 4) * 8;
      #pragma unroll
      for (int m = 0; m < 4; m++) a[m] = *(const bf16x8*)&As[(wm*64 + m*16 + (lane & 15))*64 + ko];
      #pragma unroll
      for (int n = 0; n < 4; n++) b[n] = *(const bf16x8*)&Ws[(wn*64 + n*16 + (lane & 15))*64 + ko];
      #pragma unroll
      for (int m = 0; m < 4; m++)
        #pragma unroll
        for (int n = 0; n < 4; n++)
          acc[m][n] = __builtin_amdgcn_mfma_f32_16x16x32_bf16(a[m], b[n], acc[m][n], 0, 0, 0);
    }
    __syncthreads();
  }

  // C/D layout (m89-verified): col = lane&15, row = (lane>>4)*4 + j
  const int colf = lane & 15, rowf = (lane >> 4) * 4;
  #pragma unroll
  for (int m = 0; m < 4; m++)
    #pragma unroll
    for (int n = 0; n < 4; n++) {
      long col = wrow0 + wn*64 + n*16 + colf;
      #pragma unroll
      for (int j = 0; j < 4; j++) {
        long row = arow0 + wm*64 + m*16 + rowf + j;
        long idx = row * (long)N + col;
        float v = acc[m][n][j];
        if (EPI == 0) {
          ((float*)out)[idx] = v;
        } else if (EPI == 1) {
          ((float*)out)[idx] = v + resid[idx];
        } else if (EPI == 2) {
          float t = v + bias[col];
          float ge = 0.5f * t * (1.f + erff(t * 0.70710678118654752f));
          ((short*)out)[idx] = f2bf(ge);
        } else {
          ((float*)out)[idx] = v + bias[col] + resid[idx];
        }
      }
    }
}

// ---------------- causal depthwise conv(4)+SiLU over xBC, plus softplus(dt) ----------------
__global__ __launch_bounds__(256) void conv_dt_kernel(
    const float* __restrict__ zx, const float* __restrict__ cw, const float* __restrict__ cb,
    const float* __restrict__ dt_bias,
    float* __restrict__ xh, float* __restrict__ Bo, float* __restrict__ Co, float* __restrict__ dto)
{
  int idx = blockIdx.x * 256 + threadIdx.x;   // ROWS * 2336 threads exactly
  int c2 = idx % 2336;
  int r  = idx / 2336;
  int t  = r & (L_SEQ - 1);
  if (c2 < CONVDIM) {
    float acc = cb[c2];
    #pragma unroll
    for (int k = 0; k < 4; k++) {
      int tt = t - 3 + k;
      if (tt >= 0) acc += zx[(long)(r - 3 + k)*DIN_PAD + DINNER + c2] * cw[c2*4 + k];
    }
    acc = acc / (1.f + __expf(-acc));      // SiLU
    if (c2 < DINNER)               xh[(long)r*DINNER + c2] = acc;
    else if (c2 < DINNER + DSTATE) Bo[(long)r*DSTATE + (c2 - DINNER)] = acc;
    else                           Co[(long)r*DSTATE + (c2 - DINNER - DSTATE)] = acc;
  } else {
    int h = c2 - CONVDIM;
    float v = zx[(long)r*DIN_PAD + (DINNER + CONVDIM) + h] + dt_bias[h];  // col 4352+h
    dto[(long)r*NHEADS + h] = (v > 20.f) ? v : log1pf(__expf(v));
  }
}

// ---------------- SSM scan: 1024 waves; wave = (b,h,p-quad of 4); lane = p_sub*16 + nq ----------------
// lane holds 8 states: n = nq + 16*j. y[p] = shfl_xor-reduce over nq, + D*x skip.
__global__ __launch_bounds__(64) void ssm_scan_kernel(
    const float* __restrict__ xhp, const float* __restrict__ Bm, const float* __restrict__ Cm,
    const float* __restrict__ dtb, const float* __restrict__ A_log, const float* __restrict__ Dvec,
    float* __restrict__ y)
{
  int bid = blockIdx.x;              // b*512 + h*16 + pq
  int pq = bid & 15, h = (bid >> 4) & 31, b = bid >> 9;
  int l = threadIdx.x;
  int ps = l >> 4, nq = l & 15;
  int p = pq*4 + ps;
  float a  = -__expf(A_log[h]);
  float Dh = Dvec[h];
  float s[8];
  #pragma unroll
  for (int j = 0; j < 8; j++) s[j] = 0.f;
  const long rb = (long)b * L_SEQ;
  const float* xp = xhp + rb*DINNER + h*64 + p;
  const float* bp = Bm  + rb*DSTATE + nq;
  const float* cp = Cm  + rb*DSTATE + nq;
  const float* dp = dtb + rb*NHEADS + h;
  float* yp = y + rb*DINNER + h*64 + p;

  auto loadpf = [&](long tt, float& dt_, float& x_, float* Bv, float* Cv) {
    dt_ = dp[tt*NHEADS];
    x_  = xp[tt*DINNER];
    #pragma unroll
    for (int j = 0; j < 8; j++) { Bv[j] = bp[tt*DSTATE + 16*j]; Cv[j] = cp[tt*DSTATE + 16*j]; }
  };
  auto step = [&](int t_, float dt_, float xv, const float* Bv, const float* Cv) {
    float dA = __expf(dt_ * a);
    float u  = dt_ * xv;
    float acc = 0.f;
    #pragma unroll
    for (int j = 0; j < 8; j++) {
      s[j] = fmaf(s[j], dA, u * Bv[j]);
      acc  = fmaf(s[j], Cv[j], acc);
    }
    acc += __shfl_xor(acc, 1); acc += __shfl_xor(acc, 2);
    acc += __shfl_xor(acc, 4); acc += __shfl_xor(acc, 8);
    if (nq == 0) yp[(long)t_ * DINNER] = acc + Dh * xv;
  };

  float dt0, x0, B0[8], C0[8];
  float dt1, x1, B1[8], C1[8];
  loadpf(0, dt0, x0, B0, C0);
  loadpf(1, dt1, x1, B1, C1);
  for (int t = 0; t < L_SEQ; t += 2) {
    {
      float dtc = dt0, xc = x0; float Bc[8], Cc[8];
      #pragma unroll
      for (int j = 0; j < 8; j++) { Bc[j] = B0[j]; Cc[j] = C0[j]; }
      long tn = t + 2; if (tn > L_SEQ - 1) tn = L_SEQ - 1;
      loadpf(tn, dt0, x0, B0, C0);          // 2-deep prefetch
      step(t, dtc, xc, Bc, Cc);
    }
    {
      float dtc = dt1, xc = x1; float Bc[8], Cc[8];
      #pragma unroll
      for (int j = 0; j < 8; j++) { Bc[j] = B1[j]; Cc[j] = C1[j]; }
      long tn = t + 3; if (tn > L_SEQ - 1) tn = L_SEQ - 1;
      loadpf(tn, dt1, x1, B1, C1);
      step(t + 1, dtc, xc, Bc, Cc);
    }
  }
}

// ---------------- gate with silu(z), RMS(mean) norm * mnorm_w -> bf16 ----------------
__global__ __launch_bounds__(256) void gate_mnorm_kernel(
    const float* __restrict__ y, const float* __restrict__ zx, const float* __restrict__ mw,
    short* __restrict__ out)
{
  int row = blockIdx.x, tid = threadIdx.x;
  const float* yr = y  + (long)row * DINNER;
  const float* zr = zx + (long)row * DIN_PAD;   // z = cols [0,2048)
  float g[8]; float ssum = 0.f;
  #pragma unroll
  for (int i = 0; i < 8; i++) {
    int c = tid + i*256;
    float z = zr[c];
    float v = yr[c] * (z / (1.f + __expf(-z)));
    g[i] = v; ssum += v * v;
  }
  for (int o = 32; o; o >>= 1) ssum += __shfl_down(ssum, o);
  __shared__ float red[4];
  if ((tid & 63) == 0) red[tid >> 6] = ssum;
  __syncthreads();
  float tot = red[0] + red[1] + red[2] + red[3];
  float sc = rsqrtf(tot * (1.0f / DINNER) + 1e-5f);
  #pragma unroll
  for (int i = 0; i < 8; i++) {
    int c = tid + i*256;
    out[(long)row*DINNER + c] = f2bf(g[i] * sc * mw[c]);
  }
}

extern "C" void kernel_launch(void* const* d_in, const int* in_sizes, int n_in,
                              void* d_out, int out_size, void* d_ws, size_t ws_size,
                              hipStream_t stream)
{
  const float* x        = (const float*)d_in[0];
  const float* norm1_w  = (const float*)d_in[1];
  const float* in_proj  = (const float*)d_in[2];
  const float* conv_w   = (const float*)d_in[3];
  const float* conv_b   = (const float*)d_in[4];
  const float* dt_bias  = (const float*)d_in[5];
  const float* A_log    = (const float*)d_in[6];
  const float* Dvec     = (const float*)d_in[7];
  const float* mnorm_w  = (const float*)d_in[8];
  const float* out_proj = (const float*)d_in[9];
  const float* norm2_w  = (const float*)d_in[10];
  const float* mlp_w1   = (const float*)d_in[11];
  const float* mlp_b1   = (const float*)d_in[12];
  const float* mlp_w2   = (const float*)d_in[13];
  const float* mlp_b2   = (const float*)d_in[14];
  float* outp = (float*)d_out;

  uint8_t* wsp = (uint8_t*)d_ws;
  auto take = [&](size_t bytes) { void* p = wsp; wsp += (bytes + 255) & ~(size_t)255; return p; };
  short* W1B  = (short*)take((size_t)DIN_PAD * DMODEL * 2);
  short* W2B  = (short*)take((size_t)DMODEL * DINNER * 2);
  short* W3B  = (short*)take((size_t)DMLP * DMODEL * 2);
  short* W4B  = (short*)take((size_t)DMODEL * DMLP * 2);
  short* X1B  = (short*)take((size_t)ROWS * DMODEL * 2);
  float* ZX   = (float*)take((size_t)ROWS * DIN_PAD * 4);
  float* XH   = (float*)take((size_t)ROWS * DINNER * 4);
  float* BMb  = (float*)take((size_t)ROWS * DSTATE * 4);
  float* CMb  = (float*)take((size_t)ROWS * DSTATE * 4);
  float* DTb  = (float*)take((size_t)ROWS * NHEADS * 4);
  float* Yb   = (float*)take((size_t)ROWS * DINNER * 4);
  short* YGB  = (short*)take((size_t)ROWS * DINNER * 2);
  float* X2   = (float*)take((size_t)ROWS * DMODEL * 4);
  short* X2NB = (short*)take((size_t)ROWS * DMODEL * 2);
  short* H1B  = (short*)take((size_t)ROWS * DMLP * 2);

  // weight converts (bf16, in_proj padded 4384->4480 rows with zeros)
  cvt_pad_kernel<<<2048, 256, 0, stream>>>(in_proj, W1B, DIN_PROJ, (long)DIN_PAD*DMODEL, DMODEL);
  cvt_pad_kernel<<<1024, 256, 0, stream>>>(out_proj, W2B, DMODEL, (long)DMODEL*DINNER, DINNER);
  cvt_pad_kernel<<<2048, 256, 0, stream>>>(mlp_w1, W3B, DMLP, (long)DMLP*DMODEL, DMODEL);
  cvt_pad_kernel<<<2048, 256, 0, stream>>>(mlp_w2, W4B, DMODEL, (long)DMODEL*DMLP, DMLP);

  // norm1 -> bf16
  rmsnorm_l2_kernel<<<ROWS, 256, 0, stream>>>(x, norm1_w, X1B);
  // in_proj GEMM: (4096x1024) @ (4480x1024)^T -> ZX f32
  gemm_bt_kernel<0><<<dim3(ROWS/128, DIN_PAD/128), 256, 0, stream>>>(X1B, W1B, nullptr, nullptr, ZX, DIN_PAD, DMODEL);
  // conv + dt
  conv_dt_kernel<<<(ROWS*2336)/256, 256, 0, stream>>>(ZX, conv_w, conv_b, dt_bias, XH, BMb, CMb, DTb);
  // scan
  ssm_scan_kernel<<<BATCH*NHEADS*16, 64, 0, stream>>>(XH, BMb, CMb, DTb, A_log, Dvec, Yb);
  // gate + mamba RMSNorm -> bf16
  gate_mnorm_kernel<<<ROWS, 256, 0, stream>>>(Yb, ZX, mnorm_w, YGB);
  // out_proj GEMM + residual(x) -> X2 f32
  gemm_bt_kernel<1><<<dim3(ROWS/128, DMODEL/128), 256, 0, stream>>>(YGB, W2B, nullptr, x, X2, DMODEL, DINNER);
  // norm2 -> bf16
  rmsnorm_l2_kernel<<<ROWS, 256, 0, stream>>>(X2, norm2_w, X2NB);
  // mlp1 GEMM + bias + exact gelu -> bf16
  gemm_bt_kernel<2><<<dim3(ROWS/128, DMLP/128), 256, 0, stream>>>(X2NB, W3B, mlp_b1, nullptr, H1B, DMLP, DMODEL);
  // mlp2 GEMM + bias + residual(X2) -> d_out f32
  gemm_bt_kernel<3><<<dim3(ROWS/128, DMODEL/128), 256, 0, stream>>>(H1B, W4B, mlp_b2, X2, outp, DMODEL, DMLP);
}

// Round 2
// 454.665 us; speedup vs baseline: 2.6367x; 2.6367x over previous
//
#include <hip/hip_runtime.h>
#include <hip/hip_bf16.h>
#include <cstdint>

#define L_SEQ   2048
#define BATCH   2
#define ROWS    (BATCH*L_SEQ)     // 4096
#define DMODEL  1024
#define DINNER  2048
#define DSTATE  128
#define NHEADS  32
#define DIN_PROJ 4384
#define DIN_PAD  4480             // padded to multiple of 128 for BN tiles
#define CONVDIM  2304
#define DMLP    4096
#define CHUNK   64
#define NCHUNK  (L_SEQ/CHUNK)     // 32

typedef __attribute__((ext_vector_type(4))) float f32x4;
typedef __attribute__((ext_vector_type(8))) short bf16x8;

static __device__ __forceinline__ short f2bf(float f) {
  union { float f; unsigned int i; } v; v.f = f;
  unsigned int r = v.i + 0x7fffu + ((v.i >> 16) & 1u);  // round-to-nearest-even
  return (short)(r >> 16);
}
static __device__ __forceinline__ float bf2f(short s) {
  union { unsigned int i; float f; } v; v.i = ((unsigned int)(unsigned short)s) << 16;
  return v.f;
}

static __device__ __forceinline__ void gl2lds16(const void* g, void* l) {
  __builtin_amdgcn_global_load_lds((const __attribute__((address_space(1))) void*)g,
                                   (__attribute__((address_space(3))) void*)l, 16, 0, 0);
}

// ---------------- fp32 -> bf16 weight convert with row padding ----------------
__global__ void cvt_pad_kernel(const float* __restrict__ src, short* __restrict__ dst,
                               long rows_src, long total, long K)
{
  long i = (long)blockIdx.x * 256 + threadIdx.x;
  long stride = (long)gridDim.x * 256;
  for (; i < total; i += stride) {
    long r = i / K;
    dst[i] = (r < rows_src) ? f2bf(src[i]) : (short)0;
  }
}

// ---------------- L2-style norm: w * x * rsqrt(sum(x^2) + 1e-6), D=1024 -> bf16 ----------------
__global__ __launch_bounds__(256) void rmsnorm_l2_kernel(const float* __restrict__ in,
                                                         const float* __restrict__ w,
                                                         short* __restrict__ out)
{
  int row = blockIdx.x, tid = threadIdx.x;
  const float* xr = in + (long)row * DMODEL;
  float v[4]; float s = 0.f;
  #pragma unroll
  for (int i = 0; i < 4; i++) { v[i] = xr[tid + i*256]; s += v[i]*v[i]; }
  for (int o = 32; o; o >>= 1) s += __shfl_down(s, o);
  __shared__ float red[4];
  if ((tid & 63) == 0) red[tid >> 6] = s;
  __syncthreads();
  float tot = red[0] + red[1] + red[2] + red[3];
  float sc = rsqrtf(tot + 1e-6f);
  #pragma unroll
  for (int i = 0; i < 4; i++) {
    int c = tid + i*256;
    out[(long)row*DMODEL + c] = f2bf(v[i] * sc * w[c]);
  }
}

// ---------------- bf16 GEMM: C[M,N] = A[M,K] @ W[N,K]^T, 128x128 tile, BK=64 ----------------
// EPI: 0 = store f32; 1 = +resid f32; 2 = gelu(C+bias) -> bf16; 3 = C+bias+resid -> f32
template<int EPI>
__global__ __launch_bounds__(256)
void gemm_bt_kernel(const short* __restrict__ A, const short* __restrict__ W,
                    const float* __restrict__ bias, const float* __restrict__ resid,
                    void* __restrict__ out, int N, int K)
{
  __shared__ short As[128*64];
  __shared__ short Ws[128*64];
  const int tid = threadIdx.x;
  const int lane = tid & 63, wid = tid >> 6;
  const int wm = wid >> 1, wn = wid & 1;
  const long arow0 = (long)blockIdx.x * 128;
  const long wrow0 = (long)blockIdx.y * 128;
  const int srow = tid >> 3, scol = (tid & 7) * 8;

  f32x4 acc[4][4];
  #pragma unroll
  for (int m = 0; m < 4; m++)
    #pragma unroll
    for (int n = 0; n < 4; n++)
      #pragma unroll
      for (int j = 0; j < 4; j++) acc[m][n][j] = 0.f;

  for (int kt = 0; kt < K; kt += 64) {
    #pragma unroll
    for (int i = 0; i < 4; i++) {
      const short* g = A + (arow0 + i*32 + srow) * (long)K + kt + scol;
      gl2lds16(g, &As[(i*32 + srow)*64 + scol]);
    }
    #pragma unroll
    for (int i = 0; i < 4; i++) {
      const short* g = W + (wrow0 + i*32 + srow) * (long)K + kt + scol;
      gl2lds16(g, &Ws[(i*32 + srow)*64 + scol]);
    }
    __syncthreads();
    #pragma unroll
    for (int kk = 0; kk < 64; kk += 32) {
      bf16x8 a[4], b[4];
      const int ko = kk + (lane >> 4) * 8;
      #pragma unroll
      for (int m = 0; m < 4; m++) a[m] = *(const bf16x8*)&As[(wm*64 + m*16 + (lane & 15))*64 + ko];
      #pragma unroll
      for (int n = 0; n < 4; n++) b[n] = *(const bf16x8*)&Ws[(wn*64 + n*16 + (lane & 15))*64 + ko];
      #pragma unroll
      for (int m = 0; m < 4; m++)
        #pragma unroll
        for (int n = 0; n < 4; n++)
          acc[m][n] = __builtin_amdgcn_mfma_f32_16x16x32_bf16(a[m], b[n], acc[m][n], 0, 0, 0);
    }
    __syncthreads();
  }

  const int colf = lane & 15, rowf = (lane >> 4) * 4;
  #pragma unroll
  for (int m = 0; m < 4; m++)
    #pragma unroll
    for (int n = 0; n < 4; n++) {
      long col = wrow0 + wn*64 + n*16 + colf;
      #pragma unroll
      for (int j = 0; j < 4; j++) {
        long row = arow0 + wm*64 + m*16 + rowf + j;
        long idx = row * (long)N + col;
        float v = acc[m][n][j];
        if (EPI == 0) {
          ((float*)out)[idx] = v;
        } else if (EPI == 1) {
          ((float*)out)[idx] = v + resid[idx];
        } else if (EPI == 2) {
          float t = v + bias[col];
          float ge = 0.5f * t * (1.f + erff(t * 0.70710678118654752f));
          ((short*)out)[idx] = f2bf(ge);
        } else {
          ((float*)out)[idx] = v + bias[col] + resid[idx];
        }
      }
    }
}

// ---------------- causal depthwise conv(4)+SiLU over xBC, plus softplus(dt) ----------------
__global__ __launch_bounds__(256) void conv_dt_kernel(
    const float* __restrict__ zx, const float* __restrict__ cw, const float* __restrict__ cb,
    const float* __restrict__ dt_bias,
    float* __restrict__ xh, float* __restrict__ Bo, float* __restrict__ Co, float* __restrict__ dto)
{
  int idx = blockIdx.x * 256 + threadIdx.x;   // ROWS * 2336 threads exactly
  int c2 = idx % 2336;
  int r  = idx / 2336;
  int t  = r & (L_SEQ - 1);
  if (c2 < CONVDIM) {
    float acc = cb[c2];
    #pragma unroll
    for (int k = 0; k < 4; k++) {
      int tt = t - 3 + k;
      if (tt >= 0) acc += zx[(long)(r - 3 + k)*DIN_PAD + DINNER + c2] * cw[c2*4 + k];
    }
    acc = acc / (1.f + __expf(-acc));      // SiLU
    if (c2 < DINNER)               xh[(long)r*DINNER + c2] = acc;
    else if (c2 < DINNER + DSTATE) Bo[(long)r*DSTATE + (c2 - DINNER)] = acc;
    else                           Co[(long)r*DSTATE + (c2 - DINNER - DSTATE)] = acc;
  } else {
    int h = c2 - CONVDIM;
    float v = zx[(long)r*DIN_PAD + (DINNER + CONVDIM) + h] + dt_bias[h];  // col 4352+h
    dto[(long)r*NHEADS + h] = (v > 20.f) ? v : log1pf(__expf(v));
  }
}

// ================= SSD chunked scan (replaces serial ssm_scan) =================
// Per (b,h,chunk c of 64): cs[t] = cumsum(dt*A); decay(t,tau)=e^{cs[t]-cs[tau]} (<=1).
// y[t,p] = sum_{tau<=t} e^{cs t - cs tau} dt[tau] (C_t.B_tau) x[tau,p]   (intra, MFMA)
//        + e^{cs[t]} sum_n C[t,n] Hpre[p,n]                              (inter, MFMA)
//        + D_h x[t,p]
// States: S_c[p,n] = sum_tau e^{cs[63]-cs[tau]} dt[tau] x[tau,p] B[tau,n]; Hpre recurrence over c.

// ---- K1: per-chunk cumsum + chunk states (MFMA over transposed LDS tiles) ----
__global__ __launch_bounds__(256) void ssd_states_kernel(
    const float* __restrict__ xh, const float* __restrict__ Bm,
    const float* __restrict__ dtb, const float* __restrict__ A_log,
    float* __restrict__ CS, short* __restrict__ SC)
{
  int bid = blockIdx.x;                // b*1024 + h*32 + c
  int c = bid & 31, h = (bid >> 5) & 31, b = bid >> 10;
  long r0 = (long)b * L_SEQ + c * CHUNK;
  __shared__ short XT[64*72];          // X^T [p][tau], padded stride 72 (anti-bank-conflict)
  __shared__ short BwT[128*72];        // (w*B)^T [n][tau]
  __shared__ float ws[64];
  int tid = threadIdx.x;

  if (tid < 64) {                      // wave 0: dt load + inclusive prefix sum
    float dtv = dtb[(r0 + tid)*NHEADS + h];
    float A = -__expf(A_log[h]);
    float v = dtv * A;
    #pragma unroll
    for (int o = 1; o < 64; o <<= 1) { float t = __shfl_up(v, o); if (tid >= o) v += t; }
    CS[(long)bid * 64 + tid] = v;
    float cs63 = __shfl(v, 63);
    ws[tid] = __expf(cs63 - v) * dtv;
  }
  #pragma unroll
  for (int i = 0; i < 16; i++) {       // X^T build (coalesced read, scattered LDS write)
    int e = tid + i*256, tau = e >> 6, p = e & 63;
    XT[p*72 + tau] = f2bf(xh[(r0 + tau)*DINNER + h*64 + p]);
  }
  __syncthreads();
  #pragma unroll
  for (int i = 0; i < 32; i++) {       // BwT build (needs ws)
    int e = tid + i*256, tau = e >> 7, n = e & 127;
    BwT[n*72 + tau] = f2bf(Bm[(r0 + tau)*DSTATE + n] * ws[tau]);
  }
  __syncthreads();

  int lane = tid & 63, w = tid >> 6;   // wave w owns p-rows [16w,16w+16)
  f32x4 acc[8];
  #pragma unroll
  for (int nt = 0; nt < 8; nt++) { acc[nt][0]=0.f; acc[nt][1]=0.f; acc[nt][2]=0.f; acc[nt][3]=0.f; }
  #pragma unroll
  for (int kk = 0; kk < 64; kk += 32) {
    int ko = kk + (lane >> 4) * 8;
    bf16x8 a = *(const bf16x8*)&XT[(w*16 + (lane & 15))*72 + ko];
    #pragma unroll
    for (int nt = 0; nt < 8; nt++) {
      bf16x8 bfr = *(const bf16x8*)&BwT[(nt*16 + (lane & 15))*72 + ko];
      acc[nt] = __builtin_amdgcn_mfma_f32_16x16x32_bf16(a, bfr, acc[nt], 0, 0, 0);
    }
  }
  int colf = lane & 15, rowf = (lane >> 4) * 4;
  long sbase = (long)bid * 8192;
  #pragma unroll
  for (int nt = 0; nt < 8; nt++)
    #pragma unroll
    for (int j = 0; j < 4; j++)
      SC[sbase + (w*16 + rowf + j)*128 + nt*16 + colf] = f2bf(acc[nt][j]);
}

// ---- K2: inter-chunk prefix recurrence: HP_c = pre-chunk state; H = r_c*H + S_c ----
__global__ __launch_bounds__(256) void ssd_prefix_kernel(
    const short* __restrict__ SC, const float* __restrict__ CS, short* __restrict__ HP)
{
  int bid = blockIdx.x;                // (b*32+h)*4 + q
  int q = bid & 3, bh = bid >> 2;
  int tid = threadIdx.x;
  int p = q*16 + (tid >> 4);
  int n0 = (tid & 15) * 8;
  long base = (long)bh * NCHUNK * 8192 + (long)p*128 + n0;
  float H[8];
  #pragma unroll
  for (int j = 0; j < 8; j++) H[j] = 0.f;
  for (int c = 0; c < NCHUNK; c++) {
    long idx = base + (long)c * 8192;
    bf16x8 sc = *(const bf16x8*)&SC[idx];
    bf16x8 hv;
    #pragma unroll
    for (int j = 0; j < 8; j++) hv[j] = f2bf(H[j]);
    *(bf16x8*)&HP[idx] = hv;
    float r = __expf(CS[((long)bh * NCHUNK + c)*64 + 63]);
    #pragma unroll
    for (int j = 0; j < 8; j++) H[j] = H[j]*r + bf2f(sc[j]);
  }
}

// ---- K3: per-chunk output: G=C@B^T -> mask/decay -> M@X^T + e^{cs}*(C@HP) + D*x ----
__global__ __launch_bounds__(256) void ssd_out_kernel(
    const float* __restrict__ xh, const float* __restrict__ Bm, const float* __restrict__ Cm,
    const float* __restrict__ dtb, const float* __restrict__ CS,
    const short* __restrict__ HP, const float* __restrict__ Dvec,
    float* __restrict__ y)
{
  int bid = blockIdx.x;
  int c = bid & 31, h = (bid >> 5) & 31, b = bid >> 10;
  long r0 = (long)b * L_SEQ + c * CHUNK;
  __shared__ short Csh[64*136];        // [t][n] padded stride 136
  __shared__ short Bsh[64*136];
  __shared__ short Ms[64*72];          // [t][tau]
  __shared__ short XT[64*72];          // [p][tau]
  __shared__ float csd[64], dts[64];
  int tid = threadIdx.x;

  if (tid < 64) {
    csd[tid] = CS[(long)bid*64 + tid];
    dts[tid] = dtb[(r0 + tid)*NHEADS + h];
  }
  #pragma unroll
  for (int i = 0; i < 32; i++) {
    int e = tid + i*256, tau = e >> 7, n = e & 127;
    Bsh[tau*136 + n] = f2bf(Bm[(r0 + tau)*DSTATE + n]);
    Csh[tau*136 + n] = f2bf(Cm[(r0 + tau)*DSTATE + n]);
  }
  #pragma unroll
  for (int i = 0; i < 16; i++) {
    int e = tid + i*256, tau = e >> 6, p = e & 63;
    XT[p*72 + tau] = f2bf(xh[(r0 + tau)*DINNER + h*64 + p]);
  }
  __syncthreads();

  int lane = tid & 63, w = tid >> 6;   // wave w owns t-rows [16w,16w+16)
  int colf = lane & 15, rowf = (lane >> 4) * 4;

  // G = C @ B^T over n=128
  f32x4 g[4];
  #pragma unroll
  for (int tt = 0; tt < 4; tt++) { g[tt][0]=0.f; g[tt][1]=0.f; g[tt][2]=0.f; g[tt][3]=0.f; }
  #pragma unroll
  for (int kk = 0; kk < 128; kk += 32) {
    int ko = kk + (lane >> 4) * 8;
    bf16x8 a = *(const bf16x8*)&Csh[(w*16 + (lane & 15))*136 + ko];
    #pragma unroll
    for (int tt = 0; tt < 4; tt++) {
      bf16x8 bfr = *(const bf16x8*)&Bsh[(tt*16 + (lane & 15))*136 + ko];
      g[tt] = __builtin_amdgcn_mfma_f32_16x16x32_bf16(a, bfr, g[tt], 0, 0, 0);
    }
  }
  // M = causal mask * decay * dt
  #pragma unroll
  for (int tt = 0; tt < 4; tt++)
    #pragma unroll
    for (int j = 0; j < 4; j++) {
      int trow = w*16 + rowf + j;
      int tcol = tt*16 + colf;
      float m = (tcol <= trow) ? __expf(csd[trow] - csd[tcol]) * dts[tcol] * g[tt][j] : 0.f;
      Ms[trow*72 + tcol] = f2bf(m);
    }
  __syncthreads();

  // Y = M @ X^T (K=64)  +  e^{cs[t]} * C @ HP^T (K=128)
  f32x4 yv[4], yi[4];
  #pragma unroll
  for (int pt = 0; pt < 4; pt++) {
    yv[pt][0]=0.f; yv[pt][1]=0.f; yv[pt][2]=0.f; yv[pt][3]=0.f;
    yi[pt][0]=0.f; yi[pt][1]=0.f; yi[pt][2]=0.f; yi[pt][3]=0.f;
  }
  #pragma unroll
  for (int kk = 0; kk < 64; kk += 32) {
    int ko = kk + (lane >> 4) * 8;
    bf16x8 a = *(const bf16x8*)&Ms[(w*16 + (lane & 15))*72 + ko];
    #pragma unroll
    for (int pt = 0; pt < 4; pt++) {
      bf16x8 bfr = *(const bf16x8*)&XT[(pt*16 + (lane & 15))*72 + ko];
      yv[pt] = __builtin_amdgcn_mfma_f32_16x16x32_bf16(a, bfr, yv[pt], 0, 0, 0);
    }
  }
  long hpb = (long)bid * 8192;
  #pragma unroll
  for (int kk = 0; kk < 128; kk += 32) {
    int ko = kk + (lane >> 4) * 8;
    bf16x8 a = *(const bf16x8*)&Csh[(w*16 + (lane & 15))*136 + ko];
    #pragma unroll
    for (int pt = 0; pt < 4; pt++) {
      bf16x8 bfr = *(const bf16x8*)&HP[hpb + (long)(pt*16 + (lane & 15))*128 + ko];
      yi[pt] = __builtin_amdgcn_mfma_f32_16x16x32_bf16(a, bfr, yi[pt], 0, 0, 0);
    }
  }
  float Dh = Dvec[h];
  #pragma unroll
  for (int pt = 0; pt < 4; pt++)
    #pragma unroll
    for (int j = 0; j < 4; j++) {
      int trow = w*16 + rowf + j;
      int pcol = pt*16 + colf;
      float sc_ = __expf(csd[trow]);
      long gi = (r0 + trow)*DINNER + h*64 + pcol;
      float xv = xh[gi];
      y[gi] = yv[pt][j] + sc_*yi[pt][j] + Dh*xv;
    }
}

// ---------------- gate with silu(z), RMS(mean) norm * mnorm_w -> bf16 ----------------
__global__ __launch_bounds__(256) void gate_mnorm_kernel(
    const float* __restrict__ y, const float* __restrict__ zx, const float* __restrict__ mw,
    short* __restrict__ out)
{
  int row = blockIdx.x, tid = threadIdx.x;
  const float* yr = y  + (long)row * DINNER;
  const float* zr = zx + (long)row * DIN_PAD;   // z = cols [0,2048)
  float g[8]; float ssum = 0.f;
  #pragma unroll
  for (int i = 0; i < 8; i++) {
    int c = tid + i*256;
    float z = zr[c];
    float v = yr[c] * (z / (1.f + __expf(-z)));
    g[i] = v; ssum += v * v;
  }
  for (int o = 32; o; o >>= 1) ssum += __shfl_down(ssum, o);
  __shared__ float red[4];
  if ((tid & 63) == 0) red[tid >> 6] = ssum;
  __syncthreads();
  float tot = red[0] + red[1] + red[2] + red[3];
  float sc = rsqrtf(tot * (1.0f / DINNER) + 1e-5f);
  #pragma unroll
  for (int i = 0; i < 8; i++) {
    int c = tid + i*256;
    out[(long)row*DINNER + c] = f2bf(g[i] * sc * mw[c]);
  }
}

extern "C" void kernel_launch(void* const* d_in, const int* in_sizes, int n_in,
                              void* d_out, int out_size, void* d_ws, size_t ws_size,
                              hipStream_t stream)
{
  const float* x        = (const float*)d_in[0];
  const float* norm1_w  = (const float*)d_in[1];
  const float* in_proj  = (const float*)d_in[2];
  const float* conv_w   = (const float*)d_in[3];
  const float* conv_b   = (const float*)d_in[4];
  const float* dt_bias  = (const float*)d_in[5];
  const float* A_log    = (const float*)d_in[6];
  const float* Dvec     = (const float*)d_in[7];
  const float* mnorm_w  = (const float*)d_in[8];
  const float* out_proj = (const float*)d_in[9];
  const float* norm2_w  = (const float*)d_in[10];
  const float* mlp_w1   = (const float*)d_in[11];
  const float* mlp_b1   = (const float*)d_in[12];
  const float* mlp_w2   = (const float*)d_in[13];
  const float* mlp_b2   = (const float*)d_in[14];
  float* outp = (float*)d_out;

  uint8_t* wsp = (uint8_t*)d_ws;
  auto take = [&](size_t bytes) { void* p = wsp; wsp += (bytes + 255) & ~(size_t)255; return p; };
  short* W1B  = (short*)take((size_t)DIN_PAD * DMODEL * 2);
  short* W2B  = (short*)take((size_t)DMODEL * DINNER * 2);
  short* W3B  = (short*)take((size_t)DMLP * DMODEL * 2);
  short* W4B  = (short*)take((size_t)DMODEL * DMLP * 2);
  short* X1B  = (short*)take((size_t)ROWS * DMODEL * 2);
  float* ZX   = (float*)take((size_t)ROWS * DIN_PAD * 4);
  float* XH   = (float*)take((size_t)ROWS * DINNER * 4);
  float* BMb  = (float*)take((size_t)ROWS * DSTATE * 4);
  float* CMb  = (float*)take((size_t)ROWS * DSTATE * 4);
  float* DTb  = (float*)take((size_t)ROWS * NHEADS * 4);
  float* Yb   = (float*)take((size_t)ROWS * DINNER * 4);
  short* YGB  = (short*)take((size_t)ROWS * DINNER * 2);   // 16 MB
  float* X2   = (float*)take((size_t)ROWS * DMODEL * 4);   // 16 MB (contiguous after YGB)
  short* X2NB = (short*)take((size_t)ROWS * DMODEL * 2);
  short* H1B  = (short*)take((size_t)ROWS * DMLP * 2);     // 32 MB

  // SSD scratch ALIASES (lifetimes verified disjoint):
  // SC (chunk states, 32MB bf16) <- H1B region   [SC: write K1, read K2 | H1B: write mlp1, later]
  // HP (pre-states, 32MB bf16)   <- YGB+X2 region [HP: write K2, read K3 | YGB/X2 written later]
  // CS (cumsums, 512KB f32)      <- X2NB region  [CS: write K1, read K2/K3 | X2NB written later]
  short* SC = H1B;
  short* HP = YGB;
  float* CS = (float*)X2NB;

  // weight converts (bf16, in_proj padded 4384->4480 rows with zeros)
  cvt_pad_kernel<<<2048, 256, 0, stream>>>(in_proj, W1B, DIN_PROJ, (long)DIN_PAD*DMODEL, DMODEL);
  cvt_pad_kernel<<<1024, 256, 0, stream>>>(out_proj, W2B, DMODEL, (long)DMODEL*DINNER, DINNER);
  cvt_pad_kernel<<<2048, 256, 0, stream>>>(mlp_w1, W3B, DMLP, (long)DMLP*DMODEL, DMODEL);
  cvt_pad_kernel<<<2048, 256, 0, stream>>>(mlp_w2, W4B, DMODEL, (long)DMODEL*DMLP, DMLP);

  // norm1 -> bf16
  rmsnorm_l2_kernel<<<ROWS, 256, 0, stream>>>(x, norm1_w, X1B);
  // in_proj GEMM
  gemm_bt_kernel<0><<<dim3(ROWS/128, DIN_PAD/128), 256, 0, stream>>>(X1B, W1B, nullptr, nullptr, ZX, DIN_PAD, DMODEL);
  // conv + dt
  conv_dt_kernel<<<(ROWS*2336)/256, 256, 0, stream>>>(ZX, conv_w, conv_b, dt_bias, XH, BMb, CMb, DTb);
  // SSD chunked scan
  ssd_states_kernel<<<BATCH*NHEADS*NCHUNK, 256, 0, stream>>>(XH, BMb, DTb, A_log, CS, SC);
  ssd_prefix_kernel<<<BATCH*NHEADS*4, 256, 0, stream>>>(SC, CS, HP);
  ssd_out_kernel<<<BATCH*NHEADS*NCHUNK, 256, 0, stream>>>(XH, BMb, CMb, DTb, CS, HP, Dvec, Yb);
  // gate + mamba RMSNorm -> bf16
  gate_mnorm_kernel<<<ROWS, 256, 0, stream>>>(Yb, ZX, mnorm_w, YGB);
  // out_proj GEMM + residual(x)
  gemm_bt_kernel<1><<<dim3(ROWS/128, DMODEL/128), 256, 0, stream>>>(YGB, W2B, nullptr, x, X2, DMODEL, DINNER);
  // norm2 -> bf16
  rmsnorm_l2_kernel<<<ROWS, 256, 0, stream>>>(X2, norm2_w, X2NB);
  // mlp1 GEMM + bias + exact gelu -> bf16
  gemm_bt_kernel<2><<<dim3(ROWS/128, DMLP/128), 256, 0, stream>>>(X2NB, W3B, mlp_b1, nullptr, H1B, DMLP, DMODEL);
  // mlp2 GEMM + bias + residual(X2) -> d_out f32
  gemm_bt_kernel<3><<<dim3(ROWS/128, DMODEL/128), 256, 0, stream>>>(H1B, W4B, mlp_b2, X2, outp, DMODEL, DMLP);
}

// Round 3
// 416.337 us; speedup vs baseline: 2.8794x; 1.0921x over previous
//
#include <hip/hip_runtime.h>
#include <hip/hip_bf16.h>
#include <cstdint>

#define L_SEQ   2048
#define BATCH   2
#define ROWS    (BATCH*L_SEQ)     // 4096
#define DMODEL  1024
#define DINNER  2048
#define DSTATE  128
#define NHEADS  32
#define DIN_PROJ 4384
#define DIN_PAD  4480             // padded to multiple of 128 for BN tiles
#define CONVDIM  2304
#define DMLP    4096
#define CHUNK   64
#define NCHUNK  (L_SEQ/CHUNK)     // 32

typedef __attribute__((ext_vector_type(4))) float f32x4;
typedef __attribute__((ext_vector_type(8))) short bf16x8;
typedef __attribute__((ext_vector_type(4))) short bf16x4;
typedef __attribute__((ext_vector_type(2))) short bf16x2;

static __device__ __forceinline__ short f2bf(float f) {
  union { float f; unsigned int i; } v; v.f = f;
  unsigned int r = v.i + 0x7fffu + ((v.i >> 16) & 1u);  // round-to-nearest-even
  return (short)(r >> 16);
}
static __device__ __forceinline__ float bf2f(short s) {
  union { unsigned int i; float f; } v; v.i = ((unsigned int)(unsigned short)s) << 16;
  return v.f;
}

static __device__ __forceinline__ void gl2lds16(const void* g, void* l) {
  __builtin_amdgcn_global_load_lds((const __attribute__((address_space(1))) void*)g,
                                   (__attribute__((address_space(3))) void*)l, 16, 0, 0);
}

// ---------------- fp32 -> bf16 weight convert (shift-based row calc, padded) ----------------
__global__ __launch_bounds__(256) void cvt_kernel(const float* __restrict__ src, short* __restrict__ dst,
                                                  long rows_src, int kshift)
{
  long i = (((long)blockIdx.x) * 256 + threadIdx.x) * 4;
  long r = i >> kshift;
  bf16x4 o;
  if (r < rows_src) {
    f32x4 v = *(const f32x4*)&src[i];
    o[0] = f2bf(v[0]); o[1] = f2bf(v[1]); o[2] = f2bf(v[2]); o[3] = f2bf(v[3]);
  } else {
    o[0] = 0; o[1] = 0; o[2] = 0; o[3] = 0;
  }
  *(bf16x4*)&dst[i] = o;
}

// ---------------- L2-style norm: w * x * rsqrt(sum(x^2) + 1e-6), D=1024 -> bf16 ----------------
__global__ __launch_bounds__(256) void rmsnorm_l2_kernel(const float* __restrict__ in,
                                                         const float* __restrict__ w,
                                                         short* __restrict__ out)
{
  int row = blockIdx.x, tid = threadIdx.x;
  const float* xr = in + (long)row * DMODEL;
  f32x4 v = *(const f32x4*)&xr[tid * 4];
  float s = v[0]*v[0] + v[1]*v[1] + v[2]*v[2] + v[3]*v[3];
  for (int o = 32; o; o >>= 1) s += __shfl_down(s, o);
  __shared__ float red[4];
  if ((tid & 63) == 0) red[tid >> 6] = s;
  __syncthreads();
  float sc = rsqrtf(red[0] + red[1] + red[2] + red[3] + 1e-6f);
  f32x4 wv = *(const f32x4*)&w[tid * 4];
  bf16x4 o;
  #pragma unroll
  for (int j = 0; j < 4; j++) o[j] = f2bf(v[j] * sc * wv[j]);
  *(bf16x4*)&out[(long)row * DMODEL + tid * 4] = o;
}

// ---------------- bf16 GEMM, 128x128 tile, BK=64, DOUBLE-BUFFERED + counted vmcnt ----------------
// EPI: 0 = store bf16; 1 = +resid -> f32; 2 = gelu(C+bias) -> bf16; 3 = C+bias+resid -> f32
template<int EPI>
__global__ __launch_bounds__(256)
void gemm_bt_kernel(const short* __restrict__ A, const short* __restrict__ W,
                    const float* __restrict__ bias, const float* __restrict__ resid,
                    void* __restrict__ out, int N, int K)
{
  __shared__ short As[2][128*64];
  __shared__ short Ws[2][128*64];
  const int tid = threadIdx.x;
  const int lane = tid & 63, wid = tid >> 6;
  const int wm = wid >> 1, wn = wid & 1;
  const long arow0 = (long)blockIdx.x * 128;
  const long wrow0 = (long)blockIdx.y * 128;
  const int srow = tid >> 3, scol = (tid & 7) * 8;

  f32x4 acc[4][4];
  #pragma unroll
  for (int m = 0; m < 4; m++)
    #pragma unroll
    for (int n = 0; n < 4; n++)
      #pragma unroll
      for (int j = 0; j < 4; j++) acc[m][n][j] = 0.f;

  auto stage = [&](int buf, int kt) {
    #pragma unroll
    for (int i = 0; i < 4; i++)
      gl2lds16(A + (arow0 + i*32 + srow) * (long)K + kt + scol, &As[buf][(i*32 + srow)*64 + scol]);
    #pragma unroll
    for (int i = 0; i < 4; i++)
      gl2lds16(W + (wrow0 + i*32 + srow) * (long)K + kt + scol, &Ws[buf][(i*32 + srow)*64 + scol]);
  };

  stage(0, 0);
  int cur = 0;
  for (int kt = 0; kt < K; kt += 64) {
    if (kt + 64 < K) {
      stage(cur ^ 1, kt + 64);                       // 8 more loads in flight
      asm volatile("s_waitcnt vmcnt(8)" ::: "memory"); // drain only tile-t's loads
    } else {
      asm volatile("s_waitcnt vmcnt(0)" ::: "memory");
    }
    __builtin_amdgcn_s_barrier();                    // raw barrier: no vmcnt(0) drain
    __builtin_amdgcn_sched_barrier(0);               // pin: no LDS-read hoisting above
    #pragma unroll
    for (int kk = 0; kk < 64; kk += 32) {
      bf16x8 a[4], b[4];
      const int ko = kk + (lane >> 4) * 8;
      #pragma unroll
      for (int m = 0; m < 4; m++) a[m] = *(const bf16x8*)&As[cur][(wm*64 + m*16 + (lane & 15))*64 + ko];
      #pragma unroll
      for (int n = 0; n < 4; n++) b[n] = *(const bf16x8*)&Ws[cur][(wn*64 + n*16 + (lane & 15))*64 + ko];
      #pragma unroll
      for (int m = 0; m < 4; m++)
        #pragma unroll
        for (int n = 0; n < 4; n++)
          acc[m][n] = __builtin_amdgcn_mfma_f32_16x16x32_bf16(a[m], b[n], acc[m][n], 0, 0, 0);
    }
    __builtin_amdgcn_s_barrier();                    // reads done before next overwrite
    cur ^= 1;
  }

  // C/D layout: col = lane&15, row = (lane>>4)*4 + j
  const int colf = lane & 15, rowf = (lane >> 4) * 4;
  #pragma unroll
  for (int m = 0; m < 4; m++)
    #pragma unroll
    for (int n = 0; n < 4; n++) {
      long col = wrow0 + wn*64 + n*16 + colf;
      #pragma unroll
      for (int j = 0; j < 4; j++) {
        long row = arow0 + wm*64 + m*16 + rowf + j;
        long idx = row * (long)N + col;
        float v = acc[m][n][j];
        if (EPI == 0) {
          ((short*)out)[idx] = f2bf(v);
        } else if (EPI == 1) {
          ((float*)out)[idx] = v + resid[idx];
        } else if (EPI == 2) {
          float t = v + bias[col];
          float ge = 0.5f * t * (1.f + erff(t * 0.70710678118654752f));
          ((short*)out)[idx] = f2bf(ge);
        } else {
          ((float*)out)[idx] = v + bias[col] + resid[idx];
        }
      }
    }
}

// ---------------- causal depthwise conv(4)+SiLU over xBC (bf16), plus softplus(dt) ----------------
__global__ __launch_bounds__(256) void conv_dt_kernel(
    const short* __restrict__ zx, const float* __restrict__ cw, const float* __restrict__ cb,
    const float* __restrict__ dt_bias,
    short* __restrict__ xh, short* __restrict__ Bo, short* __restrict__ Co, float* __restrict__ dto)
{
  int r = blockIdx.x;
  int t = r & (L_SEQ - 1);
  int tid = threadIdx.x;
  #pragma unroll
  for (int it = 0; it < 5; it++) {
    int u = tid + it * 256;
    if (u < 1152) {
      int c2 = u * 2;
      float a0 = cb[c2], a1 = cb[c2 + 1];
      #pragma unroll
      for (int k = 0; k < 4; k++) {
        int tt = t - 3 + k;
        if (tt >= 0) {
          bf16x2 v = *(const bf16x2*)&zx[(long)(r - 3 + k)*DIN_PAD + DINNER + c2];
          a0 += bf2f(v[0]) * cw[c2*4 + k];
          a1 += bf2f(v[1]) * cw[(c2 + 1)*4 + k];
        }
      }
      a0 = a0 / (1.f + __expf(-a0));
      a1 = a1 / (1.f + __expf(-a1));
      bf16x2 o; o[0] = f2bf(a0); o[1] = f2bf(a1);
      if (c2 < DINNER)                 *(bf16x2*)&xh[(long)r*DINNER + c2] = o;
      else if (c2 < DINNER + DSTATE)   *(bf16x2*)&Bo[(long)r*DSTATE + (c2 - DINNER)] = o;
      else                             *(bf16x2*)&Co[(long)r*DSTATE + (c2 - DINNER - DSTATE)] = o;
    } else if (u < 1168) {
      int h0 = (u - 1152) * 2;
      bf16x2 v = *(const bf16x2*)&zx[(long)r*DIN_PAD + DINNER + CONVDIM + h0];
      float v0 = bf2f(v[0]) + dt_bias[h0];
      float v1 = bf2f(v[1]) + dt_bias[h0 + 1];
      dto[(long)r*NHEADS + h0]     = (v0 > 20.f) ? v0 : log1pf(__expf(v0));
      dto[(long)r*NHEADS + h0 + 1] = (v1 > 20.f) ? v1 : log1pf(__expf(v1));
    }
  }
}

// ================= SSD chunked scan =================

// ---- K1: per-chunk cumsum + chunk states ----
__global__ __launch_bounds__(256) void ssd_states_kernel(
    const short* __restrict__ xh, const short* __restrict__ Bm,
    const float* __restrict__ dtb, const float* __restrict__ A_log,
    float* __restrict__ CS, short* __restrict__ SC)
{
  int bid = blockIdx.x;                // b*1024 + h*32 + c
  int c = bid & 31, h = (bid >> 5) & 31, b = bid >> 10;
  long r0 = (long)b * L_SEQ + c * CHUNK;
  __shared__ short XT[64*72];          // X^T [p][tau]
  __shared__ short BwT[128*72];        // (w*B)^T [n][tau]
  __shared__ float ws[64];
  int tid = threadIdx.x;

  if (tid < 64) {                      // wave 0: dt prefix sum
    float dtv = dtb[(r0 + tid)*NHEADS + h];
    float A = -__expf(A_log[h]);
    float v = dtv * A;
    #pragma unroll
    for (int o = 1; o < 64; o <<= 1) { float u = __shfl_up(v, o); if (tid >= o) v += u; }
    CS[(long)bid * 64 + tid] = v;
    float cs63 = __shfl(v, 63);
    ws[tid] = __expf(cs63 - v) * dtv;
  }
  #pragma unroll
  for (int i = 0; i < 2; i++) {        // X^T build (512 units of 8)
    int e = tid + i*256, tau = e & 63, p0 = (e >> 6) * 8;
    bf16x8 v = *(const bf16x8*)&xh[(r0 + tau)*DINNER + h*64 + p0];
    #pragma unroll
    for (int j = 0; j < 8; j++) XT[(p0 + j)*72 + tau] = v[j];
  }
  __syncthreads();
  #pragma unroll
  for (int i = 0; i < 4; i++) {        // BwT build (1024 units of 8, needs ws)
    int e = tid + i*256, tau = e & 63, n0 = (e >> 6) * 8;
    float w = ws[tau];
    bf16x8 v = *(const bf16x8*)&Bm[(r0 + tau)*DSTATE + n0];
    #pragma unroll
    for (int j = 0; j < 8; j++) BwT[(n0 + j)*72 + tau] = f2bf(bf2f(v[j]) * w);
  }
  __syncthreads();

  int lane = tid & 63, w = tid >> 6;   // wave w owns p-rows [16w,16w+16)
  f32x4 acc[8];
  #pragma unroll
  for (int nt = 0; nt < 8; nt++) { acc[nt][0]=0.f; acc[nt][1]=0.f; acc[nt][2]=0.f; acc[nt][3]=0.f; }
  #pragma unroll
  for (int kk = 0; kk < 64; kk += 32) {
    int ko = kk + (lane >> 4) * 8;
    bf16x8 a = *(const bf16x8*)&XT[(w*16 + (lane & 15))*72 + ko];
    #pragma unroll
    for (int nt = 0; nt < 8; nt++) {
      bf16x8 bfr = *(const bf16x8*)&BwT[(nt*16 + (lane & 15))*72 + ko];
      acc[nt] = __builtin_amdgcn_mfma_f32_16x16x32_bf16(a, bfr, acc[nt], 0, 0, 0);
    }
  }
  int colf = lane & 15, rowf = (lane >> 4) * 4;
  long sbase = (long)bid * 8192;
  #pragma unroll
  for (int nt = 0; nt < 8; nt++)
    #pragma unroll
    for (int j = 0; j < 4; j++)
      SC[sbase + (w*16 + rowf + j)*128 + nt*16 + colf] = f2bf(acc[nt][j]);
}

// ---- K2: inter-chunk prefix recurrence ----
__global__ __launch_bounds__(256) void ssd_prefix_kernel(
    const short* __restrict__ SC, const float* __restrict__ CS, short* __restrict__ HP)
{
  int bid = blockIdx.x;                // (b*32+h)*4 + q
  int q = bid & 3, bh = bid >> 2;
  int tid = threadIdx.x;
  int p = q*16 + (tid >> 4);
  int n0 = (tid & 15) * 8;
  long base = (long)bh * NCHUNK * 8192 + (long)p*128 + n0;
  float H[8];
  #pragma unroll
  for (int j = 0; j < 8; j++) H[j] = 0.f;
  for (int c = 0; c < NCHUNK; c++) {
    long idx = base + (long)c * 8192;
    bf16x8 sc = *(const bf16x8*)&SC[idx];
    bf16x8 hv;
    #pragma unroll
    for (int j = 0; j < 8; j++) hv[j] = f2bf(H[j]);
    *(bf16x8*)&HP[idx] = hv;
    float r = __expf(CS[((long)bh * NCHUNK + c)*64 + 63]);
    #pragma unroll
    for (int j = 0; j < 8; j++) H[j] = H[j]*r + bf2f(sc[j]);
  }
}

// ---- K3: per-chunk output ----
__global__ __launch_bounds__(256) void ssd_out_kernel(
    const short* __restrict__ xh, const short* __restrict__ Bm, const short* __restrict__ Cm,
    const float* __restrict__ dtb, const float* __restrict__ CS,
    const short* __restrict__ HP, const float* __restrict__ Dvec,
    short* __restrict__ y)
{
  int bid = blockIdx.x;
  int c = bid & 31, h = (bid >> 5) & 31, b = bid >> 10;
  long r0 = (long)b * L_SEQ + c * CHUNK;
  __shared__ short Csh[64*136];
  __shared__ short Bsh[64*136];
  __shared__ short Ms[64*72];
  __shared__ short XT[64*72];
  __shared__ float csd[64], dts[64];
  int tid = threadIdx.x;

  if (tid < 64) {
    csd[tid] = CS[(long)bid*64 + tid];
    dts[tid] = dtb[(r0 + tid)*NHEADS + h];
  }
  #pragma unroll
  for (int i = 0; i < 4; i++) {        // B/C copy (1024 units of 8)
    int e = tid + i*256, tau = e >> 4, n0 = (e & 15) * 8;
    *(bf16x8*)&Bsh[tau*136 + n0] = *(const bf16x8*)&Bm[(r0 + tau)*DSTATE + n0];
    *(bf16x8*)&Csh[tau*136 + n0] = *(const bf16x8*)&Cm[(r0 + tau)*DSTATE + n0];
  }
  #pragma unroll
  for (int i = 0; i < 2; i++) {        // X^T build
    int e = tid + i*256, tau = e & 63, p0 = (e >> 6) * 8;
    bf16x8 v = *(const bf16x8*)&xh[(r0 + tau)*DINNER + h*64 + p0];
    #pragma unroll
    for (int j = 0; j < 8; j++) XT[(p0 + j)*72 + tau] = v[j];
  }
  __syncthreads();

  int lane = tid & 63, w = tid >> 6;
  int colf = lane & 15, rowf = (lane >> 4) * 4;

  // G = C @ B^T over n=128
  f32x4 g[4];
  #pragma unroll
  for (int tt = 0; tt < 4; tt++) { g[tt][0]=0.f; g[tt][1]=0.f; g[tt][2]=0.f; g[tt][3]=0.f; }
  #pragma unroll
  for (int kk = 0; kk < 128; kk += 32) {
    int ko = kk + (lane >> 4) * 8;
    bf16x8 a = *(const bf16x8*)&Csh[(w*16 + (lane & 15))*136 + ko];
    #pragma unroll
    for (int tt = 0; tt < 4; tt++) {
      bf16x8 bfr = *(const bf16x8*)&Bsh[(tt*16 + (lane & 15))*136 + ko];
      g[tt] = __builtin_amdgcn_mfma_f32_16x16x32_bf16(a, bfr, g[tt], 0, 0, 0);
    }
  }
  // M = causal mask * decay * dt
  #pragma unroll
  for (int tt = 0; tt < 4; tt++)
    #pragma unroll
    for (int j = 0; j < 4; j++) {
      int trow = w*16 + rowf + j;
      int tcol = tt*16 + colf;
      float m = (tcol <= trow) ? __expf(csd[trow] - csd[tcol]) * dts[tcol] * g[tt][j] : 0.f;
      Ms[trow*72 + tcol] = f2bf(m);
    }
  __syncthreads();

  // Y = M @ X^T (K=64) + e^{cs[t]} * C @ HP^T (K=128)
  f32x4 yv[4], yi[4];
  #pragma unroll
  for (int pt = 0; pt < 4; pt++) {
    yv[pt][0]=0.f; yv[pt][1]=0.f; yv[pt][2]=0.f; yv[pt][3]=0.f;
    yi[pt][0]=0.f; yi[pt][1]=0.f; yi[pt][2]=0.f; yi[pt][3]=0.f;
  }
  #pragma unroll
  for (int kk = 0; kk < 64; kk += 32) {
    int ko = kk + (lane >> 4) * 8;
    bf16x8 a = *(const bf16x8*)&Ms[(w*16 + (lane & 15))*72 + ko];
    #pragma unroll
    for (int pt = 0; pt < 4; pt++) {
      bf16x8 bfr = *(const bf16x8*)&XT[(pt*16 + (lane & 15))*72 + ko];
      yv[pt] = __builtin_amdgcn_mfma_f32_16x16x32_bf16(a, bfr, yv[pt], 0, 0, 0);
    }
  }
  long hpb = (long)bid * 8192;
  #pragma unroll
  for (int kk = 0; kk < 128; kk += 32) {
    int ko = kk + (lane >> 4) * 8;
    bf16x8 a = *(const bf16x8*)&Csh[(w*16 + (lane & 15))*136 + ko];
    #pragma unroll
    for (int pt = 0; pt < 4; pt++) {
      bf16x8 bfr = *(const bf16x8*)&HP[hpb + (long)(pt*16 + (lane & 15))*128 + ko];
      yi[pt] = __builtin_amdgcn_mfma_f32_16x16x32_bf16(a, bfr, yi[pt], 0, 0, 0);
    }
  }
  float Dh = Dvec[h];
  #pragma unroll
  for (int pt = 0; pt < 4; pt++)
    #pragma unroll
    for (int j = 0; j < 4; j++) {
      int trow = w*16 + rowf + j;
      int pcol = pt*16 + colf;
      float sc_ = __expf(csd[trow]);
      float xv = bf2f(XT[pcol*72 + trow]);
      y[(r0 + trow)*DINNER + h*64 + pcol] = f2bf(yv[pt][j] + sc_*yi[pt][j] + Dh*xv);
    }
}

// ---------------- gate with silu(z), RMS(mean) norm * mnorm_w -> bf16 ----------------
__global__ __launch_bounds__(256) void gate_mnorm_kernel(
    const short* __restrict__ y, const short* __restrict__ zx, const float* __restrict__ mw,
    short* __restrict__ out)
{
  int row = blockIdx.x, tid = threadIdx.x;
  int c0 = tid * 8;
  bf16x8 yv = *(const bf16x8*)&y[(long)row*DINNER + c0];
  bf16x8 zv = *(const bf16x8*)&zx[(long)row*DIN_PAD + c0];
  float g[8]; float ssum = 0.f;
  #pragma unroll
  for (int j = 0; j < 8; j++) {
    float z = bf2f(zv[j]);
    float v = bf2f(yv[j]) * (z / (1.f + __expf(-z)));
    g[j] = v; ssum += v * v;
  }
  for (int o = 32; o; o >>= 1) ssum += __shfl_down(ssum, o);
  __shared__ float red[4];
  if ((tid & 63) == 0) red[tid >> 6] = ssum;
  __syncthreads();
  float tot = red[0] + red[1] + red[2] + red[3];
  float sc = rsqrtf(tot * (1.0f / DINNER) + 1e-5f);
  bf16x8 o;
  #pragma unroll
  for (int j = 0; j < 8; j++) o[j] = f2bf(g[j] * sc * mw[c0 + j]);
  *(bf16x8*)&out[(long)row*DINNER + c0] = o;
}

extern "C" void kernel_launch(void* const* d_in, const int* in_sizes, int n_in,
                              void* d_out, int out_size, void* d_ws, size_t ws_size,
                              hipStream_t stream)
{
  const float* x        = (const float*)d_in[0];
  const float* norm1_w  = (const float*)d_in[1];
  const float* in_proj  = (const float*)d_in[2];
  const float* conv_w   = (const float*)d_in[3];
  const float* conv_b   = (const float*)d_in[4];
  const float* dt_bias  = (const float*)d_in[5];
  const float* A_log    = (const float*)d_in[6];
  const float* Dvec     = (const float*)d_in[7];
  const float* mnorm_w  = (const float*)d_in[8];
  const float* out_proj = (const float*)d_in[9];
  const float* norm2_w  = (const float*)d_in[10];
  const float* mlp_w1   = (const float*)d_in[11];
  const float* mlp_b1   = (const float*)d_in[12];
  const float* mlp_w2   = (const float*)d_in[13];
  const float* mlp_b2   = (const float*)d_in[14];
  float* outp = (float*)d_out;

  uint8_t* wsp = (uint8_t*)d_ws;
  auto take = [&](size_t bytes) { void* p = wsp; wsp += (bytes + 255) & ~(size_t)255; return p; };
  short* W1B  = (short*)take((size_t)DIN_PAD * DMODEL * 2);
  short* W2B  = (short*)take((size_t)DMODEL * DINNER * 2);
  short* W3B  = (short*)take((size_t)DMLP * DMODEL * 2);
  short* W4B  = (short*)take((size_t)DMODEL * DMLP * 2);
  short* X1B  = (short*)take((size_t)ROWS * DMODEL * 2);
  short* ZX   = (short*)take((size_t)ROWS * DIN_PAD * 2);
  short* XH   = (short*)take((size_t)ROWS * DINNER * 2);
  short* BMb  = (short*)take((size_t)ROWS * DSTATE * 2);
  short* CMb  = (short*)take((size_t)ROWS * DSTATE * 2);
  float* DTb  = (float*)take((size_t)ROWS * NHEADS * 4);
  short* Yb   = (short*)take((size_t)ROWS * DINNER * 2);
  short* YGB  = (short*)take((size_t)ROWS * DINNER * 2);   // 16 MB
  float* X2   = (float*)take((size_t)ROWS * DMODEL * 4);   // 16 MB (contiguous after YGB)
  short* X2NB = (short*)take((size_t)ROWS * DMODEL * 2);
  short* H1B  = (short*)take((size_t)ROWS * DMLP * 2);     // 32 MB

  // SSD scratch aliases (lifetimes disjoint):
  short* SC = H1B;          // write K1, read K2   | H1B written at mlp1 (later)
  short* HP = YGB;          // write K2, read K3   | spans YGB(16MB)+X2(16MB), both written later
  float* CS = (float*)X2NB; // write K1, read K2/K3| X2NB written at norm2 (later)

  // weight converts
  cvt_kernel<<<4480, 256, 0, stream>>>(in_proj, W1B, DIN_PROJ, 10);
  cvt_kernel<<<2048, 256, 0, stream>>>(out_proj, W2B, DMODEL, 11);
  cvt_kernel<<<4096, 256, 0, stream>>>(mlp_w1, W3B, DMLP, 10);
  cvt_kernel<<<4096, 256, 0, stream>>>(mlp_w2, W4B, DMODEL, 12);

  // norm1 -> bf16
  rmsnorm_l2_kernel<<<ROWS, 256, 0, stream>>>(x, norm1_w, X1B);
  // in_proj GEMM -> ZX bf16
  gemm_bt_kernel<0><<<dim3(ROWS/128, DIN_PAD/128), 256, 0, stream>>>(X1B, W1B, nullptr, nullptr, ZX, DIN_PAD, DMODEL);
  // conv + dt
  conv_dt_kernel<<<ROWS, 256, 0, stream>>>(ZX, conv_w, conv_b, dt_bias, XH, BMb, CMb, DTb);
  // SSD chunked scan
  ssd_states_kernel<<<BATCH*NHEADS*NCHUNK, 256, 0, stream>>>(XH, BMb, DTb, A_log, CS, SC);
  ssd_prefix_kernel<<<BATCH*NHEADS*4, 256, 0, stream>>>(SC, CS, HP);
  ssd_out_kernel<<<BATCH*NHEADS*NCHUNK, 256, 0, stream>>>(XH, BMb, CMb, DTb, CS, HP, Dvec, Yb);
  // gate + mamba RMSNorm -> bf16
  gate_mnorm_kernel<<<ROWS, 256, 0, stream>>>(Yb, ZX, mnorm_w, YGB);
  // out_proj GEMM + residual(x)
  gemm_bt_kernel<1><<<dim3(ROWS/128, DMODEL/128), 256, 0, stream>>>(YGB, W2B, nullptr, x, X2, DMODEL, DINNER);
  // norm2 -> bf16
  rmsnorm_l2_kernel<<<ROWS, 256, 0, stream>>>(X2, norm2_w, X2NB);
  // mlp1 GEMM + bias + exact gelu -> bf16
  gemm_bt_kernel<2><<<dim3(ROWS/128, DMLP/128), 256, 0, stream>>>(X2NB, W3B, mlp_b1, nullptr, H1B, DMLP, DMODEL);
  // mlp2 GEMM + bias + residual(X2) -> d_out f32
  gemm_bt_kernel<3><<<dim3(ROWS/128, DMODEL/128), 256, 0, stream>>>(H1B, W4B, mlp_b2, X2, outp, DMODEL, DMLP);
}

// Round 4
// 379.351 us; speedup vs baseline: 3.1602x; 1.0975x over previous
//
#include <hip/hip_runtime.h>
#include <hip/hip_bf16.h>
#include <cstdint>

#define L_SEQ   2048
#define BATCH   2
#define ROWS    (BATCH*L_SEQ)     // 4096
#define DMODEL  1024
#define DINNER  2048
#define DSTATE  128
#define NHEADS  32
#define DIN_PROJ 4384
#define DIN_PAD  4480             // padded to multiple of 128 for BN tiles
#define CONVDIM  2304
#define DMLP    4096
#define CHUNK   64
#define NCHUNK  (L_SEQ/CHUNK)     // 32

typedef __attribute__((ext_vector_type(4))) float f32x4;
typedef __attribute__((ext_vector_type(8))) short bf16x8;
typedef __attribute__((ext_vector_type(4))) short bf16x4;
typedef __attribute__((ext_vector_type(2))) short bf16x2;

static __device__ __forceinline__ short f2bf(float f) {
  union { float f; unsigned int i; } v; v.f = f;
  unsigned int r = v.i + 0x7fffu + ((v.i >> 16) & 1u);  // round-to-nearest-even
  return (short)(r >> 16);
}
static __device__ __forceinline__ float bf2f(short s) {
  union { unsigned int i; float f; } v; v.i = ((unsigned int)(unsigned short)s) << 16;
  return v.f;
}

static __device__ __forceinline__ void gl2lds16(const void* g, void* l) {
  __builtin_amdgcn_global_load_lds((const __attribute__((address_space(1))) void*)g,
                                   (__attribute__((address_space(3))) void*)l, 16, 0, 0);
}

// ---------------- fp32 -> bf16 weight convert (shift-based row calc, padded) ----------------
__global__ __launch_bounds__(256) void cvt_kernel(const float* __restrict__ src, short* __restrict__ dst,
                                                  long rows_src, int kshift)
{
  long i = (((long)blockIdx.x) * 256 + threadIdx.x) * 4;
  long r = i >> kshift;
  bf16x4 o;
  if (r < rows_src) {
    f32x4 v = *(const f32x4*)&src[i];
    o[0] = f2bf(v[0]); o[1] = f2bf(v[1]); o[2] = f2bf(v[2]); o[3] = f2bf(v[3]);
  } else {
    o[0] = 0; o[1] = 0; o[2] = 0; o[3] = 0;
  }
  *(bf16x4*)&dst[i] = o;
}

// ---------------- L2-style norm: w * x * rsqrt(sum(x^2) + 1e-6), D=1024 -> bf16 ----------------
__global__ __launch_bounds__(256) void rmsnorm_l2_kernel(const float* __restrict__ in,
                                                         const float* __restrict__ w,
                                                         short* __restrict__ out)
{
  int row = blockIdx.x, tid = threadIdx.x;
  const float* xr = in + (long)row * DMODEL;
  f32x4 v = *(const f32x4*)&xr[tid * 4];
  float s = v[0]*v[0] + v[1]*v[1] + v[2]*v[2] + v[3]*v[3];
  for (int o = 32; o; o >>= 1) s += __shfl_down(s, o);
  __shared__ float red[4];
  if ((tid & 63) == 0) red[tid >> 6] = s;
  __syncthreads();
  float sc = rsqrtf(red[0] + red[1] + red[2] + red[3] + 1e-6f);
  f32x4 wv = *(const f32x4*)&w[tid * 4];
  bf16x4 o;
  #pragma unroll
  for (int j = 0; j < 4; j++) o[j] = f2bf(v[j] * sc * wv[j]);
  *(bf16x4*)&out[(long)row * DMODEL + tid * 4] = o;
}

// ------- bf16 GEMM, 128x128 tile, BK=64, STG-deep pipeline + T2 XOR-swizzled LDS -------
// Swizzle (rule 21): LDS dest LINEAR (global_load_lds), global SOURCE pre-swizzled by
// slot^(row&7), LDS READ swizzled by the same XOR -> bank-conflict-free ds_read_b128.
// EPI: 0 = store bf16; 1 = +resid -> f32; 2 = gelu(C+bias) -> bf16; 3 = C+bias+resid -> f32
template<int EPI, int STG>
__global__ __launch_bounds__(256)
void gemm_bt_kernel(const short* __restrict__ A, const short* __restrict__ W,
                    const float* __restrict__ bias, const float* __restrict__ resid,
                    void* __restrict__ out, int N, int K)
{
  __shared__ short As[STG][128*64];
  __shared__ short Ws[STG][128*64];
  const int tid = threadIdx.x;
  const int lane = tid & 63, wid = tid >> 6;
  const int wm = wid >> 1, wn = wid & 1;
  const long arow0 = (long)blockIdx.x * 128;
  const long wrow0 = (long)blockIdx.y * 128;
  const int srow = tid >> 3;               // 0..31
  const int sslot = (tid & 7) ^ (srow & 7); // pre-swizzled global col-block
  const int sdst = (tid >> 3) * 64 + (tid & 7) * 8;  // linear LDS dest (shorts)

  f32x4 acc[4][4];
  #pragma unroll
  for (int m = 0; m < 4; m++)
    #pragma unroll
    for (int n = 0; n < 4; n++)
      #pragma unroll
      for (int j = 0; j < 4; j++) acc[m][n][j] = 0.f;

  auto stage = [&](int buf, int kt) {
    #pragma unroll
    for (int i = 0; i < 4; i++)
      gl2lds16(A + (arow0 + i*32 + srow) * (long)K + kt + sslot*8, &As[buf][i*2048 + sdst]);
    #pragma unroll
    for (int i = 0; i < 4; i++)
      gl2lds16(W + (wrow0 + i*32 + srow) * (long)K + kt + sslot*8, &Ws[buf][i*2048 + sdst]);
  };

  const int nt = K >> 6;
  #pragma unroll
  for (int s = 0; s < STG - 1; s++) stage(s, s << 6);

  const int swz = (lane & 7) << 3;         // read-side XOR (shorts)
  for (int t = 0; t < nt; t++) {
    if (t + STG - 1 < nt) {
      stage((t + STG - 1) & (STG - 1), (t + STG - 1) << 6);
      if (STG == 4) asm volatile("s_waitcnt vmcnt(24)" ::: "memory");
      else          asm volatile("s_waitcnt vmcnt(8)"  ::: "memory");
    } else if (STG == 4 && t + 2 < nt) {
      asm volatile("s_waitcnt vmcnt(16)" ::: "memory");
    } else if (STG == 4 && t + 1 < nt) {
      asm volatile("s_waitcnt vmcnt(8)" ::: "memory");
    } else {
      asm volatile("s_waitcnt vmcnt(0)" ::: "memory");
    }
    __builtin_amdgcn_s_barrier();
    __builtin_amdgcn_sched_barrier(0);
    const int cur = t & (STG - 1);
    #pragma unroll
    for (int kk = 0; kk < 64; kk += 32) {
      bf16x8 a[4], b[4];
      const int ko = kk + (lane >> 4) * 8;
      #pragma unroll
      for (int m = 0; m < 4; m++) {
        int row = wm*64 + m*16 + (lane & 15);
        a[m] = *(const bf16x8*)&As[cur][(row*64 + ko) ^ swz];
      }
      #pragma unroll
      for (int n = 0; n < 4; n++) {
        int row = wn*64 + n*16 + (lane & 15);
        b[n] = *(const bf16x8*)&Ws[cur][(row*64 + ko) ^ swz];
      }
      #pragma unroll
      for (int m = 0; m < 4; m++)
        #pragma unroll
        for (int n = 0; n < 4; n++)
          acc[m][n] = __builtin_amdgcn_mfma_f32_16x16x32_bf16(a[m], b[n], acc[m][n], 0, 0, 0);
    }
    asm volatile("s_waitcnt lgkmcnt(0)" ::: "memory");  // reads complete before overwrite
    __builtin_amdgcn_sched_barrier(0);
    __builtin_amdgcn_s_barrier();
  }

  // C/D layout: col = lane&15, row = (lane>>4)*4 + j
  const int colf = lane & 15, rowf = (lane >> 4) * 4;
  #pragma unroll
  for (int m = 0; m < 4; m++)
    #pragma unroll
    for (int n = 0; n < 4; n++) {
      long col = wrow0 + wn*64 + n*16 + colf;
      #pragma unroll
      for (int j = 0; j < 4; j++) {
        long row = arow0 + wm*64 + m*16 + rowf + j;
        long idx = row * (long)N + col;
        float v = acc[m][n][j];
        if (EPI == 0) {
          ((short*)out)[idx] = f2bf(v);
        } else if (EPI == 1) {
          ((float*)out)[idx] = v + resid[idx];
        } else if (EPI == 2) {
          float t = v + bias[col];
          float ge = 0.5f * t * (1.f + erff(t * 0.70710678118654752f));
          ((short*)out)[idx] = f2bf(ge);
        } else {
          ((float*)out)[idx] = v + bias[col] + resid[idx];
        }
      }
    }
}

// ---------------- causal depthwise conv(4)+SiLU over xBC (bf16), plus softplus(dt) ----------------
__global__ __launch_bounds__(256) void conv_dt_kernel(
    const short* __restrict__ zx, const float* __restrict__ cw, const float* __restrict__ cb,
    const float* __restrict__ dt_bias,
    short* __restrict__ xh, short* __restrict__ Bo, short* __restrict__ Co, float* __restrict__ dto)
{
  int r = blockIdx.x;
  int t = r & (L_SEQ - 1);
  int tid = threadIdx.x;
  #pragma unroll
  for (int it = 0; it < 5; it++) {
    int u = tid + it * 256;
    if (u < 1152) {
      int c2 = u * 2;
      float a0 = cb[c2], a1 = cb[c2 + 1];
      #pragma unroll
      for (int k = 0; k < 4; k++) {
        int tt = t - 3 + k;
        if (tt >= 0) {
          bf16x2 v = *(const bf16x2*)&zx[(long)(r - 3 + k)*DIN_PAD + DINNER + c2];
          a0 += bf2f(v[0]) * cw[c2*4 + k];
          a1 += bf2f(v[1]) * cw[(c2 + 1)*4 + k];
        }
      }
      a0 = a0 / (1.f + __expf(-a0));
      a1 = a1 / (1.f + __expf(-a1));
      bf16x2 o; o[0] = f2bf(a0); o[1] = f2bf(a1);
      if (c2 < DINNER)                 *(bf16x2*)&xh[(long)r*DINNER + c2] = o;
      else if (c2 < DINNER + DSTATE)   *(bf16x2*)&Bo[(long)r*DSTATE + (c2 - DINNER)] = o;
      else                             *(bf16x2*)&Co[(long)r*DSTATE + (c2 - DINNER - DSTATE)] = o;
    } else if (u < 1168) {
      int h0 = (u - 1152) * 2;
      bf16x2 v = *(const bf16x2*)&zx[(long)r*DIN_PAD + DINNER + CONVDIM + h0];
      float v0 = bf2f(v[0]) + dt_bias[h0];
      float v1 = bf2f(v[1]) + dt_bias[h0 + 1];
      dto[(long)r*NHEADS + h0]     = (v0 > 20.f) ? v0 : log1pf(__expf(v0));
      dto[(long)r*NHEADS + h0 + 1] = (v1 > 20.f) ? v1 : log1pf(__expf(v1));
    }
  }
}

// ================= SSD chunked scan =================

// ---- K1: per-chunk cumsum + chunk states ----
__global__ __launch_bounds__(256) void ssd_states_kernel(
    const short* __restrict__ xh, const short* __restrict__ Bm,
    const float* __restrict__ dtb, const float* __restrict__ A_log,
    float* __restrict__ CS, short* __restrict__ SC)
{
  int bid = blockIdx.x;                // b*1024 + h*32 + c
  int c = bid & 31, h = (bid >> 5) & 31, b = bid >> 10;
  long r0 = (long)b * L_SEQ + c * CHUNK;
  __shared__ short XT[64*72];          // X^T [p][tau]
  __shared__ short BwT[128*72];        // (w*B)^T [n][tau]
  __shared__ float ws[64];
  int tid = threadIdx.x;

  if (tid < 64) {                      // wave 0: dt prefix sum
    float dtv = dtb[(r0 + tid)*NHEADS + h];
    float A = -__expf(A_log[h]);
    float v = dtv * A;
    #pragma unroll
    for (int o = 1; o < 64; o <<= 1) { float u = __shfl_up(v, o); if (tid >= o) v += u; }
    CS[(long)bid * 64 + tid] = v;
    float cs63 = __shfl(v, 63);
    ws[tid] = __expf(cs63 - v) * dtv;
  }
  #pragma unroll
  for (int i = 0; i < 2; i++) {        // X^T build (512 units of 8)
    int e = tid + i*256, tau = e & 63, p0 = (e >> 6) * 8;
    bf16x8 v = *(const bf16x8*)&xh[(r0 + tau)*DINNER + h*64 + p0];
    #pragma unroll
    for (int j = 0; j < 8; j++) XT[(p0 + j)*72 + tau] = v[j];
  }
  __syncthreads();
  #pragma unroll
  for (int i = 0; i < 4; i++) {        // BwT build (1024 units of 8, needs ws)
    int e = tid + i*256, tau = e & 63, n0 = (e >> 6) * 8;
    float w = ws[tau];
    bf16x8 v = *(const bf16x8*)&Bm[(r0 + tau)*DSTATE + n0];
    #pragma unroll
    for (int j = 0; j < 8; j++) BwT[(n0 + j)*72 + tau] = f2bf(bf2f(v[j]) * w);
  }
  __syncthreads();

  int lane = tid & 63, w = tid >> 6;   // wave w owns p-rows [16w,16w+16)
  f32x4 acc[8];
  #pragma unroll
  for (int nt = 0; nt < 8; nt++) { acc[nt][0]=0.f; acc[nt][1]=0.f; acc[nt][2]=0.f; acc[nt][3]=0.f; }
  #pragma unroll
  for (int kk = 0; kk < 64; kk += 32) {
    int ko = kk + (lane >> 4) * 8;
    bf16x8 a = *(const bf16x8*)&XT[(w*16 + (lane & 15))*72 + ko];
    #pragma unroll
    for (int nt = 0; nt < 8; nt++) {
      bf16x8 bfr = *(const bf16x8*)&BwT[(nt*16 + (lane & 15))*72 + ko];
      acc[nt] = __builtin_amdgcn_mfma_f32_16x16x32_bf16(a, bfr, acc[nt], 0, 0, 0);
    }
  }
  int colf = lane & 15, rowf = (lane >> 4) * 4;
  long sbase = (long)bid * 8192;
  #pragma unroll
  for (int nt = 0; nt < 8; nt++)
    #pragma unroll
    for (int j = 0; j < 4; j++)
      SC[sbase + (w*16 + rowf + j)*128 + nt*16 + colf] = f2bf(acc[nt][j]);
}

// ---- K2: inter-chunk prefix recurrence ----
__global__ __launch_bounds__(256) void ssd_prefix_kernel(
    const short* __restrict__ SC, const float* __restrict__ CS, short* __restrict__ HP)
{
  int bid = blockIdx.x;                // (b*32+h)*4 + q
  int q = bid & 3, bh = bid >> 2;
  int tid = threadIdx.x;
  int p = q*16 + (tid >> 4);
  int n0 = (tid & 15) * 8;
  long base = (long)bh * NCHUNK * 8192 + (long)p*128 + n0;
  float H[8];
  #pragma unroll
  for (int j = 0; j < 8; j++) H[j] = 0.f;
  for (int c = 0; c < NCHUNK; c++) {
    long idx = base + (long)c * 8192;
    bf16x8 sc = *(const bf16x8*)&SC[idx];
    bf16x8 hv;
    #pragma unroll
    for (int j = 0; j < 8; j++) hv[j] = f2bf(H[j]);
    *(bf16x8*)&HP[idx] = hv;
    float r = __expf(CS[((long)bh * NCHUNK + c)*64 + 63]);
    #pragma unroll
    for (int j = 0; j < 8; j++) H[j] = H[j]*r + bf2f(sc[j]);
  }
}

// ---- K3: per-chunk output ----
__global__ __launch_bounds__(256) void ssd_out_kernel(
    const short* __restrict__ xh, const short* __restrict__ Bm, const short* __restrict__ Cm,
    const float* __restrict__ dtb, const float* __restrict__ CS,
    const short* __restrict__ HP, const float* __restrict__ Dvec,
    short* __restrict__ y)
{
  int bid = blockIdx.x;
  int c = bid & 31, h = (bid >> 5) & 31, b = bid >> 10;
  long r0 = (long)b * L_SEQ + c * CHUNK;
  __shared__ short Csh[64*136];
  __shared__ short Bsh[64*136];
  __shared__ short Ms[64*72];
  __shared__ short XT[64*72];
  __shared__ float csd[64], dts[64];
  int tid = threadIdx.x;

  if (tid < 64) {
    csd[tid] = CS[(long)bid*64 + tid];
    dts[tid] = dtb[(r0 + tid)*NHEADS + h];
  }
  #pragma unroll
  for (int i = 0; i < 4; i++) {        // B/C copy (1024 units of 8)
    int e = tid + i*256, tau = e >> 4, n0 = (e & 15) * 8;
    *(bf16x8*)&Bsh[tau*136 + n0] = *(const bf16x8*)&Bm[(r0 + tau)*DSTATE + n0];
    *(bf16x8*)&Csh[tau*136 + n0] = *(const bf16x8*)&Cm[(r0 + tau)*DSTATE + n0];
  }
  #pragma unroll
  for (int i = 0; i < 2; i++) {        // X^T build
    int e = tid + i*256, tau = e & 63, p0 = (e >> 6) * 8;
    bf16x8 v = *(const bf16x8*)&xh[(r0 + tau)*DINNER + h*64 + p0];
    #pragma unroll
    for (int j = 0; j < 8; j++) XT[(p0 + j)*72 + tau] = v[j];
  }
  __syncthreads();

  int lane = tid & 63, w = tid >> 6;
  int colf = lane & 15, rowf = (lane >> 4) * 4;

  // G = C @ B^T over n=128
  f32x4 g[4];
  #pragma unroll
  for (int tt = 0; tt < 4; tt++) { g[tt][0]=0.f; g[tt][1]=0.f; g[tt][2]=0.f; g[tt][3]=0.f; }
  #pragma unroll
  for (int kk = 0; kk < 128; kk += 32) {
    int ko = kk + (lane >> 4) * 8;
    bf16x8 a = *(const bf16x8*)&Csh[(w*16 + (lane & 15))*136 + ko];
    #pragma unroll
    for (int tt = 0; tt < 4; tt++) {
      bf16x8 bfr = *(const bf16x8*)&Bsh[(tt*16 + (lane & 15))*136 + ko];
      g[tt] = __builtin_amdgcn_mfma_f32_16x16x32_bf16(a, bfr, g[tt], 0, 0, 0);
    }
  }
  // M = causal mask * decay * dt
  #pragma unroll
  for (int tt = 0; tt < 4; tt++)
    #pragma unroll
    for (int j = 0; j < 4; j++) {
      int trow = w*16 + rowf + j;
      int tcol = tt*16 + colf;
      float m = (tcol <= trow) ? __expf(csd[trow] - csd[tcol]) * dts[tcol] * g[tt][j] : 0.f;
      Ms[trow*72 + tcol] = f2bf(m);
    }
  __syncthreads();

  // Y = M @ X^T (K=64) + e^{cs[t]} * C @ HP^T (K=128)
  f32x4 yv[4], yi[4];
  #pragma unroll
  for (int pt = 0; pt < 4; pt++) {
    yv[pt][0]=0.f; yv[pt][1]=0.f; yv[pt][2]=0.f; yv[pt][3]=0.f;
    yi[pt][0]=0.f; yi[pt][1]=0.f; yi[pt][2]=0.f; yi[pt][3]=0.f;
  }
  #pragma unroll
  for (int kk = 0; kk < 64; kk += 32) {
    int ko = kk + (lane >> 4) * 8;
    bf16x8 a = *(const bf16x8*)&Ms[(w*16 + (lane & 15))*72 + ko];
    #pragma unroll
    for (int pt = 0; pt < 4; pt++) {
      bf16x8 bfr = *(const bf16x8*)&XT[(pt*16 + (lane & 15))*72 + ko];
      yv[pt] = __builtin_amdgcn_mfma_f32_16x16x32_bf16(a, bfr, yv[pt], 0, 0, 0);
    }
  }
  long hpb = (long)bid * 8192;
  #pragma unroll
  for (int kk = 0; kk < 128; kk += 32) {
    int ko = kk + (lane >> 4) * 8;
    bf16x8 a = *(const bf16x8*)&Csh[(w*16 + (lane & 15))*136 + ko];
    #pragma unroll
    for (int pt = 0; pt < 4; pt++) {
      bf16x8 bfr = *(const bf16x8*)&HP[hpb + (long)(pt*16 + (lane & 15))*128 + ko];
      yi[pt] = __builtin_amdgcn_mfma_f32_16x16x32_bf16(a, bfr, yi[pt], 0, 0, 0);
    }
  }
  float Dh = Dvec[h];
  #pragma unroll
  for (int pt = 0; pt < 4; pt++)
    #pragma unroll
    for (int j = 0; j < 4; j++) {
      int trow = w*16 + rowf + j;
      int pcol = pt*16 + colf;
      float sc_ = __expf(csd[trow]);
      float xv = bf2f(XT[pcol*72 + trow]);
      y[(r0 + trow)*DINNER + h*64 + pcol] = f2bf(yv[pt][j] + sc_*yi[pt][j] + Dh*xv);
    }
}

// ---------------- gate with silu(z), RMS(mean) norm * mnorm_w -> bf16 ----------------
__global__ __launch_bounds__(256) void gate_mnorm_kernel(
    const short* __restrict__ y, const short* __restrict__ zx, const float* __restrict__ mw,
    short* __restrict__ out)
{
  int row = blockIdx.x, tid = threadIdx.x;
  int c0 = tid * 8;
  bf16x8 yv = *(const bf16x8*)&y[(long)row*DINNER + c0];
  bf16x8 zv = *(const bf16x8*)&zx[(long)row*DIN_PAD + c0];
  float g[8]; float ssum = 0.f;
  #pragma unroll
  for (int j = 0; j < 8; j++) {
    float z = bf2f(zv[j]);
    float v = bf2f(yv[j]) * (z / (1.f + __expf(-z)));
    g[j] = v; ssum += v * v;
  }
  for (int o = 32; o; o >>= 1) ssum += __shfl_down(ssum, o);
  __shared__ float red[4];
  if ((tid & 63) == 0) red[tid >> 6] = ssum;
  __syncthreads();
  float tot = red[0] + red[1] + red[2] + red[3];
  float sc = rsqrtf(tot * (1.0f / DINNER) + 1e-5f);
  bf16x8 o;
  #pragma unroll
  for (int j = 0; j < 8; j++) o[j] = f2bf(g[j] * sc * mw[c0 + j]);
  *(bf16x8*)&out[(long)row*DINNER + c0] = o;
}

extern "C" void kernel_launch(void* const* d_in, const int* in_sizes, int n_in,
                              void* d_out, int out_size, void* d_ws, size_t ws_size,
                              hipStream_t stream)
{
  const float* x        = (const float*)d_in[0];
  const float* norm1_w  = (const float*)d_in[1];
  const float* in_proj  = (const float*)d_in[2];
  const float* conv_w   = (const float*)d_in[3];
  const float* conv_b   = (const float*)d_in[4];
  const float* dt_bias  = (const float*)d_in[5];
  const float* A_log    = (const float*)d_in[6];
  const float* Dvec     = (const float*)d_in[7];
  const float* mnorm_w  = (const float*)d_in[8];
  const float* out_proj = (const float*)d_in[9];
  const float* norm2_w  = (const float*)d_in[10];
  const float* mlp_w1   = (const float*)d_in[11];
  const float* mlp_b1   = (const float*)d_in[12];
  const float* mlp_w2   = (const float*)d_in[13];
  const float* mlp_b2   = (const float*)d_in[14];
  float* outp = (float*)d_out;

  uint8_t* wsp = (uint8_t*)d_ws;
  auto take = [&](size_t bytes) { void* p = wsp; wsp += (bytes + 255) & ~(size_t)255; return p; };
  short* W1B  = (short*)take((size_t)DIN_PAD * DMODEL * 2);
  short* W2B  = (short*)take((size_t)DMODEL * DINNER * 2);
  short* W3B  = (short*)take((size_t)DMLP * DMODEL * 2);
  short* W4B  = (short*)take((size_t)DMODEL * DMLP * 2);
  short* X1B  = (short*)take((size_t)ROWS * DMODEL * 2);
  short* ZX   = (short*)take((size_t)ROWS * DIN_PAD * 2);
  short* XH   = (short*)take((size_t)ROWS * DINNER * 2);
  short* BMb  = (short*)take((size_t)ROWS * DSTATE * 2);
  short* CMb  = (short*)take((size_t)ROWS * DSTATE * 2);
  float* DTb  = (float*)take((size_t)ROWS * NHEADS * 4);
  short* Yb   = (short*)take((size_t)ROWS * DINNER * 2);
  short* YGB  = (short*)take((size_t)ROWS * DINNER * 2);   // 16 MB
  float* X2   = (float*)take((size_t)ROWS * DMODEL * 4);   // 16 MB (contiguous after YGB)
  short* X2NB = (short*)take((size_t)ROWS * DMODEL * 2);
  short* H1B  = (short*)take((size_t)ROWS * DMLP * 2);     // 32 MB

  // SSD scratch aliases (lifetimes disjoint):
  short* SC = H1B;          // write K1, read K2   | H1B written at mlp1 (later)
  short* HP = YGB;          // write K2, read K3   | spans YGB(16MB)+X2(16MB), both written later
  float* CS = (float*)X2NB; // write K1, read K2/K3| X2NB written at norm2 (later)

  // weight converts
  cvt_kernel<<<4480, 256, 0, stream>>>(in_proj, W1B, DIN_PROJ, 10);
  cvt_kernel<<<2048, 256, 0, stream>>>(out_proj, W2B, DMODEL, 11);
  cvt_kernel<<<4096, 256, 0, stream>>>(mlp_w1, W3B, DMLP, 10);
  cvt_kernel<<<4096, 256, 0, stream>>>(mlp_w2, W4B, DMODEL, 12);

  // norm1 -> bf16
  rmsnorm_l2_kernel<<<ROWS, 256, 0, stream>>>(x, norm1_w, X1B);
  // in_proj GEMM -> ZX bf16 (grid 1120 blocks: STG=2, 64KB LDS -> 2 blocks/CU)
  gemm_bt_kernel<0,2><<<dim3(ROWS/128, DIN_PAD/128), 256, 0, stream>>>(X1B, W1B, nullptr, nullptr, ZX, DIN_PAD, DMODEL);
  // conv + dt
  conv_dt_kernel<<<ROWS, 256, 0, stream>>>(ZX, conv_w, conv_b, dt_bias, XH, BMb, CMb, DTb);
  // SSD chunked scan
  ssd_states_kernel<<<BATCH*NHEADS*NCHUNK, 256, 0, stream>>>(XH, BMb, DTb, A_log, CS, SC);
  ssd_prefix_kernel<<<BATCH*NHEADS*4, 256, 0, stream>>>(SC, CS, HP);
  ssd_out_kernel<<<BATCH*NHEADS*NCHUNK, 256, 0, stream>>>(XH, BMb, CMb, DTb, CS, HP, Dvec, Yb);
  // gate + mamba RMSNorm -> bf16
  gate_mnorm_kernel<<<ROWS, 256, 0, stream>>>(Yb, ZX, mnorm_w, YGB);
  // out_proj GEMM + residual(x) (grid 256: STG=4 deep pipeline, 1 block/CU)
  gemm_bt_kernel<1,4><<<dim3(ROWS/128, DMODEL/128), 256, 0, stream>>>(YGB, W2B, nullptr, x, X2, DMODEL, DINNER);
  // norm2 -> bf16
  rmsnorm_l2_kernel<<<ROWS, 256, 0, stream>>>(X2, norm2_w, X2NB);
  // mlp1 GEMM + bias + exact gelu -> bf16 (grid 1024: STG=2)
  gemm_bt_kernel<2,2><<<dim3(ROWS/128, DMLP/128), 256, 0, stream>>>(X2NB, W3B, mlp_b1, nullptr, H1B, DMLP, DMODEL);
  // mlp2 GEMM + bias + residual(X2) -> d_out f32 (grid 256: STG=4)
  gemm_bt_kernel<3,4><<<dim3(ROWS/128, DMODEL/128), 256, 0, stream>>>(H1B, W4B, mlp_b2, X2, outp, DMODEL, DMLP);
}

// Round 6
// 355.257 us; speedup vs baseline: 3.3745x; 1.0678x over previous
//
#include <hip/hip_runtime.h>
#include <hip/hip_bf16.h>
#include <cstdint>

#define L_SEQ   2048
#define BATCH   2
#define ROWS    (BATCH*L_SEQ)     // 4096
#define DMODEL  1024
#define DINNER  2048
#define DSTATE  128
#define NHEADS  32
#define DIN_PROJ 4384
#define DIN_PAD  4480             // padded to multiple of 128 for BN tiles
#define CONVDIM  2304
#define DMLP    4096
#define CHUNK   64
#define NCHUNK  (L_SEQ/CHUNK)     // 32

typedef __attribute__((ext_vector_type(4))) float f32x4;
typedef __attribute__((ext_vector_type(8))) short bf16x8;
typedef __attribute__((ext_vector_type(4))) short bf16x4;
typedef __attribute__((ext_vector_type(2))) short bf16x2;

static __device__ __forceinline__ short f2bf(float f) {
  union { float f; unsigned int i; } v; v.f = f;
  unsigned int r = v.i + 0x7fffu + ((v.i >> 16) & 1u);  // round-to-nearest-even
  return (short)(r >> 16);
}
static __device__ __forceinline__ float bf2f(short s) {
  union { unsigned int i; float f; } v; v.i = ((unsigned int)(unsigned short)s) << 16;
  return v.f;
}

static __device__ __forceinline__ void gl2lds16(const void* g, void* l) {
  __builtin_amdgcn_global_load_lds((const __attribute__((address_space(1))) void*)g,
                                   (__attribute__((address_space(3))) void*)l, 16, 0, 0);
}

// ---------------- fp32 -> bf16 weight convert (shift-based row calc, padded) ----------------
__global__ __launch_bounds__(256) void cvt_kernel(const float* __restrict__ src, short* __restrict__ dst,
                                                  long rows_src, int kshift)
{
  long i = (((long)blockIdx.x) * 256 + threadIdx.x) * 4;
  long r = i >> kshift;
  bf16x4 o;
  if (r < rows_src) {
    f32x4 v = *(const f32x4*)&src[i];
    o[0] = f2bf(v[0]); o[1] = f2bf(v[1]); o[2] = f2bf(v[2]); o[3] = f2bf(v[3]);
  } else {
    o[0] = 0; o[1] = 0; o[2] = 0; o[3] = 0;
  }
  *(bf16x4*)&dst[i] = o;
}

// ---------------- L2-style norm: w * x * rsqrt(sum(x^2) + 1e-6), D=1024 -> bf16 ----------------
__global__ __launch_bounds__(256) void rmsnorm_l2_kernel(const float* __restrict__ in,
                                                         const float* __restrict__ w,
                                                         short* __restrict__ out)
{
  int row = blockIdx.x, tid = threadIdx.x;
  const float* xr = in + (long)row * DMODEL;
  f32x4 v = *(const f32x4*)&xr[tid * 4];
  float s = v[0]*v[0] + v[1]*v[1] + v[2]*v[2] + v[3]*v[3];
  for (int o = 32; o; o >>= 1) s += __shfl_down(s, o);
  __shared__ float red[4];
  if ((tid & 63) == 0) red[tid >> 6] = s;
  __syncthreads();
  float sc = rsqrtf(red[0] + red[1] + red[2] + red[3] + 1e-6f);
  f32x4 wv = *(const f32x4*)&w[tid * 4];
  bf16x4 o;
  #pragma unroll
  for (int j = 0; j < 4; j++) o[j] = f2bf(v[j] * sc * wv[j]);
  *(bf16x4*)&out[(long)row * DMODEL + tid * 4] = o;
}

// ------- bf16 GEMM, 128x128 tile, BK=64, STG-deep pipeline + T2 XOR-swizzled LDS -------
// EPI: 0 = store bf16; 1 = +resid -> f32; 2 = gelu(C+bias) -> bf16; 3 = C+bias+resid -> f32
template<int EPI, int STG>
__global__ __launch_bounds__(256)
void gemm_bt_kernel(const short* __restrict__ A, const short* __restrict__ W,
                    const float* __restrict__ bias, const float* __restrict__ resid,
                    void* __restrict__ out, int N, int K)
{
  __shared__ short As[STG][128*64];
  __shared__ short Ws[STG][128*64];
  const int tid = threadIdx.x;
  const int lane = tid & 63, wid = tid >> 6;
  const int wm = wid >> 1, wn = wid & 1;
  const long arow0 = (long)blockIdx.x * 128;
  const long wrow0 = (long)blockIdx.y * 128;
  const int srow = tid >> 3;               // 0..31
  const int sslot = (tid & 7) ^ (srow & 7); // pre-swizzled global col-block
  const int sdst = (tid >> 3) * 64 + (tid & 7) * 8;  // linear LDS dest (shorts)

  f32x4 acc[4][4];
  #pragma unroll
  for (int m = 0; m < 4; m++)
    #pragma unroll
    for (int n = 0; n < 4; n++)
      #pragma unroll
      for (int j = 0; j < 4; j++) acc[m][n][j] = 0.f;

  auto stage = [&](int buf, int kt) {
    #pragma unroll
    for (int i = 0; i < 4; i++)
      gl2lds16(A + (arow0 + i*32 + srow) * (long)K + kt + sslot*8, &As[buf][i*2048 + sdst]);
    #pragma unroll
    for (int i = 0; i < 4; i++)
      gl2lds16(W + (wrow0 + i*32 + srow) * (long)K + kt + sslot*8, &Ws[buf][i*2048 + sdst]);
  };

  const int nt = K >> 6;
  #pragma unroll
  for (int s = 0; s < STG - 1; s++) stage(s, s << 6);

  const int swz = (lane & 7) << 3;         // read-side XOR (shorts)
  for (int t = 0; t < nt; t++) {
    if (t + STG - 1 < nt) {
      stage((t + STG - 1) & (STG - 1), (t + STG - 1) << 6);
      if (STG == 4) asm volatile("s_waitcnt vmcnt(24)" ::: "memory");
      else          asm volatile("s_waitcnt vmcnt(8)"  ::: "memory");
    } else if (STG == 4 && t + 2 < nt) {
      asm volatile("s_waitcnt vmcnt(16)" ::: "memory");
    } else if (STG == 4 && t + 1 < nt) {
      asm volatile("s_waitcnt vmcnt(8)" ::: "memory");
    } else {
      asm volatile("s_waitcnt vmcnt(0)" ::: "memory");
    }
    __builtin_amdgcn_s_barrier();
    __builtin_amdgcn_sched_barrier(0);
    const int cur = t & (STG - 1);
    #pragma unroll
    for (int kk = 0; kk < 64; kk += 32) {
      bf16x8 a[4], b[4];
      const int ko = kk + (lane >> 4) * 8;
      #pragma unroll
      for (int m = 0; m < 4; m++) {
        int row = wm*64 + m*16 + (lane & 15);
        a[m] = *(const bf16x8*)&As[cur][(row*64 + ko) ^ swz];
      }
      #pragma unroll
      for (int n = 0; n < 4; n++) {
        int row = wn*64 + n*16 + (lane & 15);
        b[n] = *(const bf16x8*)&Ws[cur][(row*64 + ko) ^ swz];
      }
      #pragma unroll
      for (int m = 0; m < 4; m++)
        #pragma unroll
        for (int n = 0; n < 4; n++)
          acc[m][n] = __builtin_amdgcn_mfma_f32_16x16x32_bf16(a[m], b[n], acc[m][n], 0, 0, 0);
    }
    asm volatile("s_waitcnt lgkmcnt(0)" ::: "memory");  // reads complete before overwrite
    __builtin_amdgcn_sched_barrier(0);
    __builtin_amdgcn_s_barrier();
  }

  // C/D layout: col = lane&15, row = (lane>>4)*4 + j
  const int colf = lane & 15, rowf = (lane >> 4) * 4;
  #pragma unroll
  for (int m = 0; m < 4; m++)
    #pragma unroll
    for (int n = 0; n < 4; n++) {
      long col = wrow0 + wn*64 + n*16 + colf;
      #pragma unroll
      for (int j = 0; j < 4; j++) {
        long row = arow0 + wm*64 + m*16 + rowf + j;
        long idx = row * (long)N + col;
        float v = acc[m][n][j];
        if (EPI == 0) {
          ((short*)out)[idx] = f2bf(v);
        } else if (EPI == 1) {
          ((float*)out)[idx] = v + resid[idx];
        } else if (EPI == 2) {
          float t = v + bias[col];
          float ge = 0.5f * t * (1.f + erff(t * 0.70710678118654752f));
          ((short*)out)[idx] = f2bf(ge);
        } else {
          ((float*)out)[idx] = v + bias[col] + resid[idx];
        }
      }
    }
}

// ------- causal depthwise conv(4)+SiLU, 8-row x 8-ch tiles, zero-padded halo; + softplus(dt) -------
// Block = 8 consecutive rows (512 blocks). Thread owns 8 channels; 11-row sliding window
// loaded once as bf16x8 (vs 4 taps x 4B before: ~7x fewer load instrs, no tap re-fetch).
__global__ __launch_bounds__(256) void conv_dt_kernel(
    const short* __restrict__ zx, const float* __restrict__ cw, const float* __restrict__ cb,
    const float* __restrict__ dt_bias,
    short* __restrict__ xh, short* __restrict__ Bo, short* __restrict__ Co, float* __restrict__ dto)
{
  const int r0 = blockIdx.x * 8;
  const int tid = threadIdx.x;
  const bool interior = (r0 & (L_SEQ - 1)) != 0;   // batch-start blocks zero-fill halo

  auto conv8 = [&](int c0, auto&& emit) {
    const long col = DINNER + c0;
    f32x4 w[8]; float cbv[8];
    #pragma unroll
    for (int j = 0; j < 8; j++) { w[j] = *(const f32x4*)&cw[(c0 + j) * 4]; cbv[j] = cb[c0 + j]; }
    bf16x8 win[11];                      // win[j] = row r0-3+j (zero-pad == reference's jnp.pad)
    #pragma unroll
    for (int j = 0; j < 3; j++) {
      bf16x8 z;
      #pragma unroll
      for (int q = 0; q < 8; q++) z[q] = 0;
      win[j] = interior ? *(const bf16x8*)&zx[(long)(r0 - 3 + j) * DIN_PAD + col] : z;
    }
    #pragma unroll
    for (int j = 3; j < 11; j++)
      win[j] = *(const bf16x8*)&zx[(long)(r0 - 3 + j) * DIN_PAD + col];
    #pragma unroll
    for (int i = 0; i < 8; i++) {        // output rows r0+i; tap k uses win[i+k]
      float a[8];
      #pragma unroll
      for (int j = 0; j < 8; j++) a[j] = cbv[j];
      #pragma unroll
      for (int k = 0; k < 4; k++)
        #pragma unroll
        for (int j = 0; j < 8; j++) a[j] = fmaf(bf2f(win[i + k][j]), w[j][k], a[j]);
      bf16x8 o;
      #pragma unroll
      for (int j = 0; j < 8; j++) { float s = a[j] / (1.f + __expf(-a[j])); o[j] = f2bf(s); }
      emit(i, o);
    }
  };

  // pass A: xh channels [0,2048), all 256 threads
  {
    int c0 = tid * 8;
    conv8(c0, [&](int i, bf16x8 o) {
      *(bf16x8*)&xh[(long)(r0 + i) * DINNER + c0] = o;
    });
  }
  // pass B: B/C channels [2048,2304), threads 0..31
  if (tid < 32) {
    int c0 = 2048 + tid * 8;
    conv8(c0, [&](int i, bf16x8 o) {
      if (c0 < 2048 + DSTATE) *(bf16x8*)&Bo[(long)(r0 + i) * DSTATE + (c0 - 2048)] = o;
      else                    *(bf16x8*)&Co[(long)(r0 + i) * DSTATE + (c0 - 2048 - DSTATE)] = o;
    });
  } else if (tid < 36) {
    // pass C: dt softplus, 4 threads x 8 heads
    int h0 = (tid - 32) * 8;
    float db[8];
    #pragma unroll
    for (int j = 0; j < 8; j++) db[j] = dt_bias[h0 + j];
    #pragma unroll
    for (int i = 0; i < 8; i++) {
      bf16x8 v = *(const bf16x8*)&zx[(long)(r0 + i) * DIN_PAD + (DINNER + CONVDIM) + h0];
      f32x4 o0, o1;
      #pragma unroll
      for (int j = 0; j < 8; j++) {
        float t = bf2f(v[j]) + db[j];
        float sp = (t > 20.f) ? t : log1pf(__expf(t));
        if (j < 4) o0[j] = sp; else o1[j - 4] = sp;
      }
      *(f32x4*)&dto[(long)(r0 + i) * NHEADS + h0] = o0;
      *(f32x4*)&dto[(long)(r0 + i) * NHEADS + h0 + 4] = o1;
    }
  }
}

// ================= SSD chunked scan =================

// ---- K1: per-chunk cumsum + chunk states ----
__global__ __launch_bounds__(256) void ssd_states_kernel(
    const short* __restrict__ xh, const short* __restrict__ Bm,
    const float* __restrict__ dtb, const float* __restrict__ A_log,
    float* __restrict__ CS, short* __restrict__ SC)
{
  int bid = blockIdx.x;                // b*1024 + h*32 + c
  int c = bid & 31, h = (bid >> 5) & 31, b = bid >> 10;
  long r0 = (long)b * L_SEQ + c * CHUNK;
  __shared__ short XT[64*72];          // X^T [p][tau]
  __shared__ short BwT[128*72];        // (w*B)^T [n][tau]
  __shared__ float ws[64];
  int tid = threadIdx.x;

  if (tid < 64) {                      // wave 0: dt prefix sum
    float dtv = dtb[(r0 + tid)*NHEADS + h];
    float A = -__expf(A_log[h]);
    float v = dtv * A;
    #pragma unroll
    for (int o = 1; o < 64; o <<= 1) { float u = __shfl_up(v, o); if (tid >= o) v += u; }
    CS[(long)bid * 64 + tid] = v;
    float cs63 = __shfl(v, 63);
    ws[tid] = __expf(cs63 - v) * dtv;
  }
  #pragma unroll
  for (int i = 0; i < 2; i++) {        // X^T build (512 units of 8)
    int e = tid + i*256, tau = e & 63, p0 = (e >> 6) * 8;
    bf16x8 v = *(const bf16x8*)&xh[(r0 + tau)*DINNER + h*64 + p0];
    #pragma unroll
    for (int j = 0; j < 8; j++) XT[(p0 + j)*72 + tau] = v[j];
  }
  __syncthreads();
  #pragma unroll
  for (int i = 0; i < 4; i++) {        // BwT build (1024 units of 8, needs ws)
    int e = tid + i*256, tau = e & 63, n0 = (e >> 6) * 8;
    float w = ws[tau];
    bf16x8 v = *(const bf16x8*)&Bm[(r0 + tau)*DSTATE + n0];
    #pragma unroll
    for (int j = 0; j < 8; j++) BwT[(n0 + j)*72 + tau] = f2bf(bf2f(v[j]) * w);
  }
  __syncthreads();

  int lane = tid & 63, w = tid >> 6;   // wave w owns p-rows [16w,16w+16)
  f32x4 acc[8];
  #pragma unroll
  for (int nt = 0; nt < 8; nt++) { acc[nt][0]=0.f; acc[nt][1]=0.f; acc[nt][2]=0.f; acc[nt][3]=0.f; }
  #pragma unroll
  for (int kk = 0; kk < 64; kk += 32) {
    int ko = kk + (lane >> 4) * 8;
    bf16x8 a = *(const bf16x8*)&XT[(w*16 + (lane & 15))*72 + ko];
    #pragma unroll
    for (int nt = 0; nt < 8; nt++) {
      bf16x8 bfr = *(const bf16x8*)&BwT[(nt*16 + (lane & 15))*72 + ko];
      acc[nt] = __builtin_amdgcn_mfma_f32_16x16x32_bf16(a, bfr, acc[nt], 0, 0, 0);
    }
  }
  int colf = lane & 15, rowf = (lane >> 4) * 4;
  long sbase = (long)bid * 8192;
  #pragma unroll
  for (int nt = 0; nt < 8; nt++)
    #pragma unroll
    for (int j = 0; j < 4; j++)
      SC[sbase + (w*16 + rowf + j)*128 + nt*16 + colf] = f2bf(acc[nt][j]);
}

// ---- K2: inter-chunk prefix recurrence ----
__global__ __launch_bounds__(256) void ssd_prefix_kernel(
    const short* __restrict__ SC, const float* __restrict__ CS, short* __restrict__ HP)
{
  int bid = blockIdx.x;                // (b*32+h)*4 + q
  int q = bid & 3, bh = bid >> 2;
  int tid = threadIdx.x;
  int p = q*16 + (tid >> 4);
  int n0 = (tid & 15) * 8;
  long base = (long)bh * NCHUNK * 8192 + (long)p*128 + n0;
  float H[8];
  #pragma unroll
  for (int j = 0; j < 8; j++) H[j] = 0.f;
  for (int c = 0; c < NCHUNK; c++) {
    long idx = base + (long)c * 8192;
    bf16x8 sc = *(const bf16x8*)&SC[idx];
    bf16x8 hv;
    #pragma unroll
    for (int j = 0; j < 8; j++) hv[j] = f2bf(H[j]);
    *(bf16x8*)&HP[idx] = hv;
    float r = __expf(CS[((long)bh * NCHUNK + c)*64 + 63]);
    #pragma unroll
    for (int j = 0; j < 8; j++) H[j] = H[j]*r + bf2f(sc[j]);
  }
}

// ---- K3: per-chunk output ----
__global__ __launch_bounds__(256) void ssd_out_kernel(
    const short* __restrict__ xh, const short* __restrict__ Bm, const short* __restrict__ Cm,
    const float* __restrict__ dtb, const float* __restrict__ CS,
    const short* __restrict__ HP, const float* __restrict__ Dvec,
    short* __restrict__ y)
{
  int bid = blockIdx.x;
  int c = bid & 31, h = (bid >> 5) & 31, b = bid >> 10;
  long r0 = (long)b * L_SEQ + c * CHUNK;
  __shared__ short Csh[64*136];
  __shared__ short Bsh[64*136];
  __shared__ short Ms[64*72];
  __shared__ short XT[64*72];
  __shared__ float csd[64], dts[64];
  int tid = threadIdx.x;

  if (tid < 64) {
    csd[tid] = CS[(long)bid*64 + tid];
    dts[tid] = dtb[(r0 + tid)*NHEADS + h];
  }
  #pragma unroll
  for (int i = 0; i < 4; i++) {        // B/C copy (1024 units of 8)
    int e = tid + i*256, tau = e >> 4, n0 = (e & 15) * 8;
    *(bf16x8*)&Bsh[tau*136 + n0] = *(const bf16x8*)&Bm[(r0 + tau)*DSTATE + n0];
    *(bf16x8*)&Csh[tau*136 + n0] = *(const bf16x8*)&Cm[(r0 + tau)*DSTATE + n0];
  }
  #pragma unroll
  for (int i = 0; i < 2; i++) {        // X^T build
    int e = tid + i*256, tau = e & 63, p0 = (e >> 6) * 8;
    bf16x8 v = *(const bf16x8*)&xh[(r0 + tau)*DINNER + h*64 + p0];
    #pragma unroll
    for (int j = 0; j < 8; j++) XT[(p0 + j)*72 + tau] = v[j];
  }
  __syncthreads();

  int lane = tid & 63, w = tid >> 6;
  int colf = lane & 15, rowf = (lane >> 4) * 4;

  // G = C @ B^T over n=128
  f32x4 g[4];
  #pragma unroll
  for (int tt = 0; tt < 4; tt++) { g[tt][0]=0.f; g[tt][1]=0.f; g[tt][2]=0.f; g[tt][3]=0.f; }
  #pragma unroll
  for (int kk = 0; kk < 128; kk += 32) {
    int ko = kk + (lane >> 4) * 8;
    bf16x8 a = *(const bf16x8*)&Csh[(w*16 + (lane & 15))*136 + ko];
    #pragma unroll
    for (int tt = 0; tt < 4; tt++) {
      bf16x8 bfr = *(const bf16x8*)&Bsh[(tt*16 + (lane & 15))*136 + ko];
      g[tt] = __builtin_amdgcn_mfma_f32_16x16x32_bf16(a, bfr, g[tt], 0, 0, 0);
    }
  }
  // M = causal mask * decay * dt
  #pragma unroll
  for (int tt = 0; tt < 4; tt++)
    #pragma unroll
    for (int j = 0; j < 4; j++) {
      int trow = w*16 + rowf + j;
      int tcol = tt*16 + colf;
      float m = (tcol <= trow) ? __expf(csd[trow] - csd[tcol]) * dts[tcol] * g[tt][j] : 0.f;
      Ms[trow*72 + tcol] = f2bf(m);
    }
  __syncthreads();

  // Y = M @ X^T (K=64) + e^{cs[t]} * C @ HP^T (K=128)
  f32x4 yv[4], yi[4];
  #pragma unroll
  for (int pt = 0; pt < 4; pt++) {
    yv[pt][0]=0.f; yv[pt][1]=0.f; yv[pt][2]=0.f; yv[pt][3]=0.f;
    yi[pt][0]=0.f; yi[pt][1]=0.f; yi[pt][2]=0.f; yi[pt][3]=0.f;
  }
  #pragma unroll
  for (int kk = 0; kk < 64; kk += 32) {
    int ko = kk + (lane >> 4) * 8;
    bf16x8 a = *(const bf16x8*)&Ms[(w*16 + (lane & 15))*72 + ko];
    #pragma unroll
    for (int pt = 0; pt < 4; pt++) {
      bf16x8 bfr = *(const bf16x8*)&XT[(pt*16 + (lane & 15))*72 + ko];
      yv[pt] = __builtin_amdgcn_mfma_f32_16x16x32_bf16(a, bfr, yv[pt], 0, 0, 0);
    }
  }
  long hpb = (long)bid * 8192;
  #pragma unroll
  for (int kk = 0; kk < 128; kk += 32) {
    int ko = kk + (lane >> 4) * 8;
    bf16x8 a = *(const bf16x8*)&Csh[(w*16 + (lane & 15))*136 + ko];
    #pragma unroll
    for (int pt = 0; pt < 4; pt++) {
      bf16x8 bfr = *(const bf16x8*)&HP[hpb + (long)(pt*16 + (lane & 15))*128 + ko];
      yi[pt] = __builtin_amdgcn_mfma_f32_16x16x32_bf16(a, bfr, yi[pt], 0, 0, 0);
    }
  }
  float Dh = Dvec[h];
  #pragma unroll
  for (int pt = 0; pt < 4; pt++)
    #pragma unroll
    for (int j = 0; j < 4; j++) {
      int trow = w*16 + rowf + j;
      int pcol = pt*16 + colf;
      float sc_ = __expf(csd[trow]);
      float xv = bf2f(XT[pcol*72 + trow]);
      y[(r0 + trow)*DINNER + h*64 + pcol] = f2bf(yv[pt][j] + sc_*yi[pt][j] + Dh*xv);
    }
}

// ---------------- gate with silu(z), RMS(mean) norm * mnorm_w -> bf16 ----------------
__global__ __launch_bounds__(256) void gate_mnorm_kernel(
    const short* __restrict__ y, const short* __restrict__ zx, const float* __restrict__ mw,
    short* __restrict__ out)
{
  int row = blockIdx.x, tid = threadIdx.x;
  int c0 = tid * 8;
  bf16x8 yv = *(const bf16x8*)&y[(long)row*DINNER + c0];
  bf16x8 zv = *(const bf16x8*)&zx[(long)row*DIN_PAD + c0];
  float g[8]; float ssum = 0.f;
  #pragma unroll
  for (int j = 0; j < 8; j++) {
    float z = bf2f(zv[j]);
    float v = bf2f(yv[j]) * (z / (1.f + __expf(-z)));
    g[j] = v; ssum += v * v;
  }
  for (int o = 32; o; o >>= 1) ssum += __shfl_down(ssum, o);
  __shared__ float red[4];
  if ((tid & 63) == 0) red[tid >> 6] = ssum;
  __syncthreads();
  float tot = red[0] + red[1] + red[2] + red[3];
  float sc = rsqrtf(tot * (1.0f / DINNER) + 1e-5f);
  bf16x8 o;
  #pragma unroll
  for (int j = 0; j < 8; j++) o[j] = f2bf(g[j] * sc * mw[c0 + j]);
  *(bf16x8*)&out[(long)row*DINNER + c0] = o;
}

extern "C" void kernel_launch(void* const* d_in, const int* in_sizes, int n_in,
                              void* d_out, int out_size, void* d_ws, size_t ws_size,
                              hipStream_t stream)
{
  const float* x        = (const float*)d_in[0];
  const float* norm1_w  = (const float*)d_in[1];
  const float* in_proj  = (const float*)d_in[2];
  const float* conv_w   = (const float*)d_in[3];
  const float* conv_b   = (const float*)d_in[4];
  const float* dt_bias  = (const float*)d_in[5];
  const float* A_log    = (const float*)d_in[6];
  const float* Dvec     = (const float*)d_in[7];
  const float* mnorm_w  = (const float*)d_in[8];
  const float* out_proj = (const float*)d_in[9];
  const float* norm2_w  = (const float*)d_in[10];
  const float* mlp_w1   = (const float*)d_in[11];
  const float* mlp_b1   = (const float*)d_in[12];
  const float* mlp_w2   = (const float*)d_in[13];
  const float* mlp_b2   = (const float*)d_in[14];
  float* outp = (float*)d_out;

  uint8_t* wsp = (uint8_t*)d_ws;
  auto take = [&](size_t bytes) { void* p = wsp; wsp += (bytes + 255) & ~(size_t)255; return p; };
  short* W1B  = (short*)take((size_t)DIN_PAD * DMODEL * 2);
  short* W2B  = (short*)take((size_t)DMODEL * DINNER * 2);
  short* W3B  = (short*)take((size_t)DMLP * DMODEL * 2);
  short* W4B  = (short*)take((size_t)DMODEL * DMLP * 2);
  short* X1B  = (short*)take((size_t)ROWS * DMODEL * 2);
  short* ZX   = (short*)take((size_t)ROWS * DIN_PAD * 2);
  short* XH   = (short*)take((size_t)ROWS * DINNER * 2);
  short* BMb  = (short*)take((size_t)ROWS * DSTATE * 2);
  short* CMb  = (short*)take((size_t)ROWS * DSTATE * 2);
  float* DTb  = (float*)take((size_t)ROWS * NHEADS * 4);
  short* Yb   = (short*)take((size_t)ROWS * DINNER * 2);
  short* YGB  = (short*)take((size_t)ROWS * DINNER * 2);   // 16 MB
  float* X2   = (float*)take((size_t)ROWS * DMODEL * 4);   // 16 MB (contiguous after YGB)
  short* X2NB = (short*)take((size_t)ROWS * DMODEL * 2);
  short* H1B  = (short*)take((size_t)ROWS * DMLP * 2);     // 32 MB

  // SSD scratch aliases (lifetimes disjoint):
  short* SC = H1B;          // write K1, read K2   | H1B written at mlp1 (later)
  short* HP = YGB;          // write K2, read K3   | spans YGB(16MB)+X2(16MB), both written later
  float* CS = (float*)X2NB; // write K1, read K2/K3| X2NB written at norm2 (later)

  // weight converts
  cvt_kernel<<<4480, 256, 0, stream>>>(in_proj, W1B, DIN_PROJ, 10);
  cvt_kernel<<<2048, 256, 0, stream>>>(out_proj, W2B, DMODEL, 11);
  cvt_kernel<<<4096, 256, 0, stream>>>(mlp_w1, W3B, DMLP, 10);
  cvt_kernel<<<4096, 256, 0, stream>>>(mlp_w2, W4B, DMODEL, 12);

  // norm1 -> bf16
  rmsnorm_l2_kernel<<<ROWS, 256, 0, stream>>>(x, norm1_w, X1B);
  // in_proj GEMM -> ZX bf16 (STG=2)
  gemm_bt_kernel<0,2><<<dim3(ROWS/128, DIN_PAD/128), 256, 0, stream>>>(X1B, W1B, nullptr, nullptr, ZX, DIN_PAD, DMODEL);
  // conv + dt (8-row blocks)
  conv_dt_kernel<<<ROWS/8, 256, 0, stream>>>(ZX, conv_w, conv_b, dt_bias, XH, BMb, CMb, DTb);
  // SSD chunked scan
  ssd_states_kernel<<<BATCH*NHEADS*NCHUNK, 256, 0, stream>>>(XH, BMb, DTb, A_log, CS, SC);
  ssd_prefix_kernel<<<BATCH*NHEADS*4, 256, 0, stream>>>(SC, CS, HP);
  ssd_out_kernel<<<BATCH*NHEADS*NCHUNK, 256, 0, stream>>>(XH, BMb, CMb, DTb, CS, HP, Dvec, Yb);
  // gate + mamba RMSNorm -> bf16
  gate_mnorm_kernel<<<ROWS, 256, 0, stream>>>(Yb, ZX, mnorm_w, YGB);
  // out_proj GEMM + residual(x) (STG=4 deep pipeline)
  gemm_bt_kernel<1,4><<<dim3(ROWS/128, DMODEL/128), 256, 0, stream>>>(YGB, W2B, nullptr, x, X2, DMODEL, DINNER);
  // norm2 -> bf16
  rmsnorm_l2_kernel<<<ROWS, 256, 0, stream>>>(X2, norm2_w, X2NB);
  // mlp1 GEMM + bias + exact gelu -> bf16 (STG=2)
  gemm_bt_kernel<2,2><<<dim3(ROWS/128, DMLP/128), 256, 0, stream>>>(X2NB, W3B, mlp_b1, nullptr, H1B, DMLP, DMODEL);
  // mlp2 GEMM + bias + residual(X2) -> d_out f32 (STG=4)
  gemm_bt_kernel<3,4><<<dim3(ROWS/128, DMODEL/128), 256, 0, stream>>>(H1B, W4B, mlp_b2, X2, outp, DMODEL, DMLP);
}

// Round 7
// 337.581 us; speedup vs baseline: 3.5512x; 1.0524x over previous
//
#include <hip/hip_runtime.h>
#include <hip/hip_bf16.h>
#include <cstdint>

#define L_SEQ   2048
#define BATCH   2
#define ROWS    (BATCH*L_SEQ)     // 4096
#define DMODEL  1024
#define DINNER  2048
#define DSTATE  128
#define NHEADS  32
#define DIN_PROJ 4384
#define DIN_PAD  4480             // padded to multiple of 128 for BN tiles
#define CONVDIM  2304
#define DMLP    4096
#define CHUNK   64
#define NCHUNK  (L_SEQ/CHUNK)     // 32

typedef __attribute__((ext_vector_type(4))) float f32x4;
typedef __attribute__((ext_vector_type(8))) short bf16x8;
typedef __attribute__((ext_vector_type(4))) short bf16x4;
typedef __attribute__((ext_vector_type(2))) short bf16x2;

static __device__ __forceinline__ short f2bf(float f) {
  union { float f; unsigned int i; } v; v.f = f;
  unsigned int r = v.i + 0x7fffu + ((v.i >> 16) & 1u);  // round-to-nearest-even
  return (short)(r >> 16);
}
static __device__ __forceinline__ float bf2f(short s) {
  union { unsigned int i; float f; } v; v.i = ((unsigned int)(unsigned short)s) << 16;
  return v.f;
}

static __device__ __forceinline__ void gl2lds16(const void* g, void* l) {
  __builtin_amdgcn_global_load_lds((const __attribute__((address_space(1))) void*)g,
                                   (__attribute__((address_space(3))) void*)l, 16, 0, 0);
}

// ---------------- fp32 -> bf16 weight convert (shift-based row calc, padded) ----------------
__global__ __launch_bounds__(256) void cvt_kernel(const float* __restrict__ src, short* __restrict__ dst,
                                                  long rows_src, int kshift)
{
  long i = (((long)blockIdx.x) * 256 + threadIdx.x) * 4;
  long r = i >> kshift;
  bf16x4 o;
  if (r < rows_src) {
    f32x4 v = *(const f32x4*)&src[i];
    o[0] = f2bf(v[0]); o[1] = f2bf(v[1]); o[2] = f2bf(v[2]); o[3] = f2bf(v[3]);
  } else {
    o[0] = 0; o[1] = 0; o[2] = 0; o[3] = 0;
  }
  *(bf16x4*)&dst[i] = o;
}

// ---------------- L2-style norm: w * x * rsqrt(sum(x^2) + 1e-6), D=1024 -> bf16 ----------------
__global__ __launch_bounds__(256) void rmsnorm_l2_kernel(const float* __restrict__ in,
                                                         const float* __restrict__ w,
                                                         short* __restrict__ out)
{
  int row = blockIdx.x, tid = threadIdx.x;
  const float* xr = in + (long)row * DMODEL;
  f32x4 v = *(const f32x4*)&xr[tid * 4];
  float s = v[0]*v[0] + v[1]*v[1] + v[2]*v[2] + v[3]*v[3];
  for (int o = 32; o; o >>= 1) s += __shfl_down(s, o);
  __shared__ float red[4];
  if ((tid & 63) == 0) red[tid >> 6] = s;
  __syncthreads();
  float sc = rsqrtf(red[0] + red[1] + red[2] + red[3] + 1e-6f);
  f32x4 wv = *(const f32x4*)&w[tid * 4];
  bf16x4 o;
  #pragma unroll
  for (int j = 0; j < 4; j++) o[j] = f2bf(v[j] * sc * wv[j]);
  *(bf16x4*)&out[(long)row * DMODEL + tid * 4] = o;
}

// ------- bf16 GEMM, 128x128 tile, BK=64, STG-deep pipeline + T2 XOR-swizzled LDS -------
// Split-K via gridDim.z: each z-slice computes K/gridDim.z and (EPI=4) writes f32 partials.
// EPI: 0 = store bf16; 2 = gelu(C+bias) -> bf16; 4 = f32 partial (split-K)
template<int EPI, int STG>
__global__ __launch_bounds__(256)
void gemm_bt_kernel(const short* __restrict__ A, const short* __restrict__ W,
                    const float* __restrict__ bias, const float* __restrict__ resid,
                    void* __restrict__ out, int N, int K)
{
  __shared__ short As[STG][128*64];
  __shared__ short Ws[STG][128*64];
  const int tid = threadIdx.x;
  const int lane = tid & 63, wid = tid >> 6;
  const int wm = wid >> 1, wn = wid & 1;
  const long arow0 = (long)blockIdx.x * 128;
  const long wrow0 = (long)blockIdx.y * 128;
  const int srow = tid >> 3;               // 0..31
  const int sslot = (tid & 7) ^ (srow & 7); // pre-swizzled global col-block
  const int sdst = (tid >> 3) * 64 + (tid & 7) * 8;  // linear LDS dest (shorts)

  const int Keff = K / gridDim.z;
  const long kbase = (long)blockIdx.z * Keff;

  f32x4 acc[4][4];
  #pragma unroll
  for (int m = 0; m < 4; m++)
    #pragma unroll
    for (int n = 0; n < 4; n++)
      #pragma unroll
      for (int j = 0; j < 4; j++) acc[m][n][j] = 0.f;

  auto stage = [&](int buf, long kt) {
    #pragma unroll
    for (int i = 0; i < 4; i++)
      gl2lds16(A + (arow0 + i*32 + srow) * (long)K + kt + sslot*8, &As[buf][i*2048 + sdst]);
    #pragma unroll
    for (int i = 0; i < 4; i++)
      gl2lds16(W + (wrow0 + i*32 + srow) * (long)K + kt + sslot*8, &Ws[buf][i*2048 + sdst]);
  };

  const int nt = Keff >> 6;
  #pragma unroll
  for (int s = 0; s < STG - 1; s++) stage(s, kbase + (s << 6));

  const int swz = (lane & 7) << 3;         // read-side XOR (shorts)
  for (int t = 0; t < nt; t++) {
    if (t + STG - 1 < nt) {
      stage((t + STG - 1) & (STG - 1), kbase + ((long)(t + STG - 1) << 6));
      if (STG == 4) asm volatile("s_waitcnt vmcnt(24)" ::: "memory");
      else          asm volatile("s_waitcnt vmcnt(8)"  ::: "memory");
    } else if (STG == 4 && t + 2 < nt) {
      asm volatile("s_waitcnt vmcnt(16)" ::: "memory");
    } else if (STG == 4 && t + 1 < nt) {
      asm volatile("s_waitcnt vmcnt(8)" ::: "memory");
    } else {
      asm volatile("s_waitcnt vmcnt(0)" ::: "memory");
    }
    __builtin_amdgcn_s_barrier();
    __builtin_amdgcn_sched_barrier(0);
    const int cur = t & (STG - 1);
    #pragma unroll
    for (int kk = 0; kk < 64; kk += 32) {
      bf16x8 a[4], b[4];
      const int ko = kk + (lane >> 4) * 8;
      #pragma unroll
      for (int m = 0; m < 4; m++) {
        int row = wm*64 + m*16 + (lane & 15);
        a[m] = *(const bf16x8*)&As[cur][(row*64 + ko) ^ swz];
      }
      #pragma unroll
      for (int n = 0; n < 4; n++) {
        int row = wn*64 + n*16 + (lane & 15);
        b[n] = *(const bf16x8*)&Ws[cur][(row*64 + ko) ^ swz];
      }
      #pragma unroll
      for (int m = 0; m < 4; m++)
        #pragma unroll
        for (int n = 0; n < 4; n++)
          acc[m][n] = __builtin_amdgcn_mfma_f32_16x16x32_bf16(a[m], b[n], acc[m][n], 0, 0, 0);
    }
    asm volatile("s_waitcnt lgkmcnt(0)" ::: "memory");  // reads complete before overwrite
    __builtin_amdgcn_sched_barrier(0);
    __builtin_amdgcn_s_barrier();
  }

  // C/D layout: col = lane&15, row = (lane>>4)*4 + j
  const int colf = lane & 15, rowf = (lane >> 4) * 4;
  const long psliceoff = (long)blockIdx.z * ((long)gridDim.x * 128) * N;
  #pragma unroll
  for (int m = 0; m < 4; m++)
    #pragma unroll
    for (int n = 0; n < 4; n++) {
      long col = wrow0 + wn*64 + n*16 + colf;
      #pragma unroll
      for (int j = 0; j < 4; j++) {
        long row = arow0 + wm*64 + m*16 + rowf + j;
        long idx = row * (long)N + col;
        float v = acc[m][n][j];
        if (EPI == 0) {
          ((short*)out)[idx] = f2bf(v);
        } else if (EPI == 2) {
          float t = v + bias[col];
          float ge = 0.5f * t * (1.f + erff(t * 0.70710678118654752f));
          ((short*)out)[idx] = f2bf(ge);
        } else {
          ((float*)out)[psliceoff + idx] = v;   // EPI==4: f32 partial
        }
      }
    }
}

// ---------------- split-2 reduce: out = p0 + p1 + resid (+ bias) ----------------
template<bool BIAS>
__global__ __launch_bounds__(256) void reduce_split2_kernel(
    const float* __restrict__ part, const float* __restrict__ resid,
    const float* __restrict__ bias, float* __restrict__ out)
{
  long i = ((long)blockIdx.x * 256 + threadIdx.x) * 4;
  f32x4 p0 = *(const f32x4*)&part[i];
  f32x4 p1 = *(const f32x4*)&part[i + (long)ROWS * DMODEL];
  f32x4 r  = *(const f32x4*)&resid[i];
  f32x4 o;
  if (BIAS) {
    f32x4 bv = *(const f32x4*)&bias[(int)(i & (DMODEL - 1))];
    #pragma unroll
    for (int j = 0; j < 4; j++) o[j] = p0[j] + p1[j] + r[j] + bv[j];
  } else {
    #pragma unroll
    for (int j = 0; j < 4; j++) o[j] = p0[j] + p1[j] + r[j];
  }
  *(f32x4*)&out[i] = o;
}

// ------- causal depthwise conv(4)+SiLU, 8-row x 8-ch tiles, zero-padded halo; + softplus(dt) -------
__global__ __launch_bounds__(256) void conv_dt_kernel(
    const short* __restrict__ zx, const float* __restrict__ cw, const float* __restrict__ cb,
    const float* __restrict__ dt_bias,
    short* __restrict__ xh, short* __restrict__ Bo, short* __restrict__ Co, float* __restrict__ dto)
{
  const int r0 = blockIdx.x * 8;
  const int tid = threadIdx.x;
  const bool interior = (r0 & (L_SEQ - 1)) != 0;   // batch-start blocks zero-fill halo

  auto conv8 = [&](int c0, auto&& emit) {
    const long col = DINNER + c0;
    f32x4 w[8]; float cbv[8];
    #pragma unroll
    for (int j = 0; j < 8; j++) { w[j] = *(const f32x4*)&cw[(c0 + j) * 4]; cbv[j] = cb[c0 + j]; }
    bf16x8 win[11];                      // win[j] = row r0-3+j (zero-pad == reference's jnp.pad)
    #pragma unroll
    for (int j = 0; j < 3; j++) {
      bf16x8 z;
      #pragma unroll
      for (int q = 0; q < 8; q++) z[q] = 0;
      win[j] = interior ? *(const bf16x8*)&zx[(long)(r0 - 3 + j) * DIN_PAD + col] : z;
    }
    #pragma unroll
    for (int j = 3; j < 11; j++)
      win[j] = *(const bf16x8*)&zx[(long)(r0 - 3 + j) * DIN_PAD + col];
    #pragma unroll
    for (int i = 0; i < 8; i++) {        // output rows r0+i; tap k uses win[i+k]
      float a[8];
      #pragma unroll
      for (int j = 0; j < 8; j++) a[j] = cbv[j];
      #pragma unroll
      for (int k = 0; k < 4; k++)
        #pragma unroll
        for (int j = 0; j < 8; j++) a[j] = fmaf(bf2f(win[i + k][j]), w[j][k], a[j]);
      bf16x8 o;
      #pragma unroll
      for (int j = 0; j < 8; j++) { float s = a[j] / (1.f + __expf(-a[j])); o[j] = f2bf(s); }
      emit(i, o);
    }
  };

  // pass A: xh channels [0,2048), all 256 threads
  {
    int c0 = tid * 8;
    conv8(c0, [&](int i, bf16x8 o) {
      *(bf16x8*)&xh[(long)(r0 + i) * DINNER + c0] = o;
    });
  }
  // pass B: B/C channels [2048,2304), threads 0..31
  if (tid < 32) {
    int c0 = 2048 + tid * 8;
    conv8(c0, [&](int i, bf16x8 o) {
      if (c0 < 2048 + DSTATE) *(bf16x8*)&Bo[(long)(r0 + i) * DSTATE + (c0 - 2048)] = o;
      else                    *(bf16x8*)&Co[(long)(r0 + i) * DSTATE + (c0 - 2048 - DSTATE)] = o;
    });
  } else if (tid < 36) {
    // pass C: dt softplus, 4 threads x 8 heads
    int h0 = (tid - 32) * 8;
    float db[8];
    #pragma unroll
    for (int j = 0; j < 8; j++) db[j] = dt_bias[h0 + j];
    #pragma unroll
    for (int i = 0; i < 8; i++) {
      bf16x8 v = *(const bf16x8*)&zx[(long)(r0 + i) * DIN_PAD + (DINNER + CONVDIM) + h0];
      f32x4 o0, o1;
      #pragma unroll
      for (int j = 0; j < 8; j++) {
        float t = bf2f(v[j]) + db[j];
        float sp = (t > 20.f) ? t : log1pf(__expf(t));
        if (j < 4) o0[j] = sp; else o1[j - 4] = sp;
      }
      *(f32x4*)&dto[(long)(r0 + i) * NHEADS + h0] = o0;
      *(f32x4*)&dto[(long)(r0 + i) * NHEADS + h0 + 4] = o1;
    }
  }
}

// ================= SSD chunked scan =================

// ---- K1: per-chunk cumsum + chunk states ----
__global__ __launch_bounds__(256) void ssd_states_kernel(
    const short* __restrict__ xh, const short* __restrict__ Bm,
    const float* __restrict__ dtb, const float* __restrict__ A_log,
    float* __restrict__ CS, short* __restrict__ SC)
{
  int bid = blockIdx.x;                // b*1024 + h*32 + c
  int c = bid & 31, h = (bid >> 5) & 31, b = bid >> 10;
  long r0 = (long)b * L_SEQ + c * CHUNK;
  __shared__ short XT[64*72];          // X^T [p][tau]
  __shared__ short BwT[128*72];        // (w*B)^T [n][tau]
  __shared__ float ws[64];
  int tid = threadIdx.x;

  if (tid < 64) {                      // wave 0: dt prefix sum
    float dtv = dtb[(r0 + tid)*NHEADS + h];
    float A = -__expf(A_log[h]);
    float v = dtv * A;
    #pragma unroll
    for (int o = 1; o < 64; o <<= 1) { float u = __shfl_up(v, o); if (tid >= o) v += u; }
    CS[(long)bid * 64 + tid] = v;
    float cs63 = __shfl(v, 63);
    ws[tid] = __expf(cs63 - v) * dtv;
  }
  #pragma unroll
  for (int i = 0; i < 2; i++) {        // X^T build (512 units of 8)
    int e = tid + i*256, tau = e & 63, p0 = (e >> 6) * 8;
    bf16x8 v = *(const bf16x8*)&xh[(r0 + tau)*DINNER + h*64 + p0];
    #pragma unroll
    for (int j = 0; j < 8; j++) XT[(p0 + j)*72 + tau] = v[j];
  }
  __syncthreads();
  #pragma unroll
  for (int i = 0; i < 4; i++) {        // BwT build (1024 units of 8, needs ws)
    int e = tid + i*256, tau = e & 63, n0 = (e >> 6) * 8;
    float w = ws[tau];
    bf16x8 v = *(const bf16x8*)&Bm[(r0 + tau)*DSTATE + n0];
    #pragma unroll
    for (int j = 0; j < 8; j++) BwT[(n0 + j)*72 + tau] = f2bf(bf2f(v[j]) * w);
  }
  __syncthreads();

  int lane = tid & 63, w = tid >> 6;   // wave w owns p-rows [16w,16w+16)
  f32x4 acc[8];
  #pragma unroll
  for (int nt = 0; nt < 8; nt++) { acc[nt][0]=0.f; acc[nt][1]=0.f; acc[nt][2]=0.f; acc[nt][3]=0.f; }
  #pragma unroll
  for (int kk = 0; kk < 64; kk += 32) {
    int ko = kk + (lane >> 4) * 8;
    bf16x8 a = *(const bf16x8*)&XT[(w*16 + (lane & 15))*72 + ko];
    #pragma unroll
    for (int nt = 0; nt < 8; nt++) {
      bf16x8 bfr = *(const bf16x8*)&BwT[(nt*16 + (lane & 15))*72 + ko];
      acc[nt] = __builtin_amdgcn_mfma_f32_16x16x32_bf16(a, bfr, acc[nt], 0, 0, 0);
    }
  }
  int colf = lane & 15, rowf = (lane >> 4) * 4;
  long sbase = (long)bid * 8192;
  #pragma unroll
  for (int nt = 0; nt < 8; nt++)
    #pragma unroll
    for (int j = 0; j < 4; j++)
      SC[sbase + (w*16 + rowf + j)*128 + nt*16 + colf] = f2bf(acc[nt][j]);
}

// ---- K2: inter-chunk prefix recurrence ----
__global__ __launch_bounds__(256) void ssd_prefix_kernel(
    const short* __restrict__ SC, const float* __restrict__ CS, short* __restrict__ HP)
{
  int bid = blockIdx.x;                // (b*32+h)*4 + q
  int q = bid & 3, bh = bid >> 2;
  int tid = threadIdx.x;
  int p = q*16 + (tid >> 4);
  int n0 = (tid & 15) * 8;
  long base = (long)bh * NCHUNK * 8192 + (long)p*128 + n0;
  float H[8];
  #pragma unroll
  for (int j = 0; j < 8; j++) H[j] = 0.f;
  for (int c = 0; c < NCHUNK; c++) {
    long idx = base + (long)c * 8192;
    bf16x8 sc = *(const bf16x8*)&SC[idx];
    bf16x8 hv;
    #pragma unroll
    for (int j = 0; j < 8; j++) hv[j] = f2bf(H[j]);
    *(bf16x8*)&HP[idx] = hv;
    float r = __expf(CS[((long)bh * NCHUNK + c)*64 + 63]);
    #pragma unroll
    for (int j = 0; j < 8; j++) H[j] = H[j]*r + bf2f(sc[j]);
  }
}

// ---- K3: per-chunk output ----
__global__ __launch_bounds__(256) void ssd_out_kernel(
    const short* __restrict__ xh, const short* __restrict__ Bm, const short* __restrict__ Cm,
    const float* __restrict__ dtb, const float* __restrict__ CS,
    const short* __restrict__ HP, const float* __restrict__ Dvec,
    short* __restrict__ y)
{
  int bid = blockIdx.x;
  int c = bid & 31, h = (bid >> 5) & 31, b = bid >> 10;
  long r0 = (long)b * L_SEQ + c * CHUNK;
  __shared__ short Csh[64*136];
  __shared__ short Bsh[64*136];
  __shared__ short Ms[64*72];
  __shared__ short XT[64*72];
  __shared__ float csd[64], dts[64];
  int tid = threadIdx.x;

  if (tid < 64) {
    csd[tid] = CS[(long)bid*64 + tid];
    dts[tid] = dtb[(r0 + tid)*NHEADS + h];
  }
  #pragma unroll
  for (int i = 0; i < 4; i++) {        // B/C copy (1024 units of 8)
    int e = tid + i*256, tau = e >> 4, n0 = (e & 15) * 8;
    *(bf16x8*)&Bsh[tau*136 + n0] = *(const bf16x8*)&Bm[(r0 + tau)*DSTATE + n0];
    *(bf16x8*)&Csh[tau*136 + n0] = *(const bf16x8*)&Cm[(r0 + tau)*DSTATE + n0];
  }
  #pragma unroll
  for (int i = 0; i < 2; i++) {        // X^T build
    int e = tid + i*256, tau = e & 63, p0 = (e >> 6) * 8;
    bf16x8 v = *(const bf16x8*)&xh[(r0 + tau)*DINNER + h*64 + p0];
    #pragma unroll
    for (int j = 0; j < 8; j++) XT[(p0 + j)*72 + tau] = v[j];
  }
  __syncthreads();

  int lane = tid & 63, w = tid >> 6;
  int colf = lane & 15, rowf = (lane >> 4) * 4;

  // G = C @ B^T over n=128
  f32x4 g[4];
  #pragma unroll
  for (int tt = 0; tt < 4; tt++) { g[tt][0]=0.f; g[tt][1]=0.f; g[tt][2]=0.f; g[tt][3]=0.f; }
  #pragma unroll
  for (int kk = 0; kk < 128; kk += 32) {
    int ko = kk + (lane >> 4) * 8;
    bf16x8 a = *(const bf16x8*)&Csh[(w*16 + (lane & 15))*136 + ko];
    #pragma unroll
    for (int tt = 0; tt < 4; tt++) {
      bf16x8 bfr = *(const bf16x8*)&Bsh[(tt*16 + (lane & 15))*136 + ko];
      g[tt] = __builtin_amdgcn_mfma_f32_16x16x32_bf16(a, bfr, g[tt], 0, 0, 0);
    }
  }
  // M = causal mask * decay * dt
  #pragma unroll
  for (int tt = 0; tt < 4; tt++)
    #pragma unroll
    for (int j = 0; j < 4; j++) {
      int trow = w*16 + rowf + j;
      int tcol = tt*16 + colf;
      float m = (tcol <= trow) ? __expf(csd[trow] - csd[tcol]) * dts[tcol] * g[tt][j] : 0.f;
      Ms[trow*72 + tcol] = f2bf(m);
    }
  __syncthreads();

  // Y = M @ X^T (K=64) + e^{cs[t]} * C @ HP^T (K=128)
  f32x4 yv[4], yi[4];
  #pragma unroll
  for (int pt = 0; pt < 4; pt++) {
    yv[pt][0]=0.f; yv[pt][1]=0.f; yv[pt][2]=0.f; yv[pt][3]=0.f;
    yi[pt][0]=0.f; yi[pt][1]=0.f; yi[pt][2]=0.f; yi[pt][3]=0.f;
  }
  #pragma unroll
  for (int kk = 0; kk < 64; kk += 32) {
    int ko = kk + (lane >> 4) * 8;
    bf16x8 a = *(const bf16x8*)&Ms[(w*16 + (lane & 15))*72 + ko];
    #pragma unroll
    for (int pt = 0; pt < 4; pt++) {
      bf16x8 bfr = *(const bf16x8*)&XT[(pt*16 + (lane & 15))*72 + ko];
      yv[pt] = __builtin_amdgcn_mfma_f32_16x16x32_bf16(a, bfr, yv[pt], 0, 0, 0);
    }
  }
  long hpb = (long)bid * 8192;
  #pragma unroll
  for (int kk = 0; kk < 128; kk += 32) {
    int ko = kk + (lane >> 4) * 8;
    bf16x8 a = *(const bf16x8*)&Csh[(w*16 + (lane & 15))*136 + ko];
    #pragma unroll
    for (int pt = 0; pt < 4; pt++) {
      bf16x8 bfr = *(const bf16x8*)&HP[hpb + (long)(pt*16 + (lane & 15))*128 + ko];
      yi[pt] = __builtin_amdgcn_mfma_f32_16x16x32_bf16(a, bfr, yi[pt], 0, 0, 0);
    }
  }
  float Dh = Dvec[h];
  #pragma unroll
  for (int pt = 0; pt < 4; pt++)
    #pragma unroll
    for (int j = 0; j < 4; j++) {
      int trow = w*16 + rowf + j;
      int pcol = pt*16 + colf;
      float sc_ = __expf(csd[trow]);
      float xv = bf2f(XT[pcol*72 + trow]);
      y[(r0 + trow)*DINNER + h*64 + pcol] = f2bf(yv[pt][j] + sc_*yi[pt][j] + Dh*xv);
    }
}

// ---------------- gate with silu(z), RMS(mean) norm * mnorm_w -> bf16 ----------------
__global__ __launch_bounds__(256) void gate_mnorm_kernel(
    const short* __restrict__ y, const short* __restrict__ zx, const float* __restrict__ mw,
    short* __restrict__ out)
{
  int row = blockIdx.x, tid = threadIdx.x;
  int c0 = tid * 8;
  bf16x8 yv = *(const bf16x8*)&y[(long)row*DINNER + c0];
  bf16x8 zv = *(const bf16x8*)&zx[(long)row*DIN_PAD + c0];
  float g[8]; float ssum = 0.f;
  #pragma unroll
  for (int j = 0; j < 8; j++) {
    float z = bf2f(zv[j]);
    float v = bf2f(yv[j]) * (z / (1.f + __expf(-z)));
    g[j] = v; ssum += v * v;
  }
  for (int o = 32; o; o >>= 1) ssum += __shfl_down(ssum, o);
  __shared__ float red[4];
  if ((tid & 63) == 0) red[tid >> 6] = ssum;
  __syncthreads();
  float tot = red[0] + red[1] + red[2] + red[3];
  float sc = rsqrtf(tot * (1.0f / DINNER) + 1e-5f);
  bf16x8 o;
  #pragma unroll
  for (int j = 0; j < 8; j++) o[j] = f2bf(g[j] * sc * mw[c0 + j]);
  *(bf16x8*)&out[(long)row*DINNER + c0] = o;
}

extern "C" void kernel_launch(void* const* d_in, const int* in_sizes, int n_in,
                              void* d_out, int out_size, void* d_ws, size_t ws_size,
                              hipStream_t stream)
{
  const float* x        = (const float*)d_in[0];
  const float* norm1_w  = (const float*)d_in[1];
  const float* in_proj  = (const float*)d_in[2];
  const float* conv_w   = (const float*)d_in[3];
  const float* conv_b   = (const float*)d_in[4];
  const float* dt_bias  = (const float*)d_in[5];
  const float* A_log    = (const float*)d_in[6];
  const float* Dvec     = (const float*)d_in[7];
  const float* mnorm_w  = (const float*)d_in[8];
  const float* out_proj = (const float*)d_in[9];
  const float* norm2_w  = (const float*)d_in[10];
  const float* mlp_w1   = (const float*)d_in[11];
  const float* mlp_b1   = (const float*)d_in[12];
  const float* mlp_w2   = (const float*)d_in[13];
  const float* mlp_b2   = (const float*)d_in[14];
  float* outp = (float*)d_out;

  uint8_t* wsp = (uint8_t*)d_ws;
  auto take = [&](size_t bytes) { void* p = wsp; wsp += (bytes + 255) & ~(size_t)255; return p; };
  short* W1B  = (short*)take((size_t)DIN_PAD * DMODEL * 2);
  short* W2B  = (short*)take((size_t)DMODEL * DINNER * 2);
  short* W3B  = (short*)take((size_t)DMLP * DMODEL * 2);
  short* W4B  = (short*)take((size_t)DMODEL * DMLP * 2);
  short* X1B  = (short*)take((size_t)ROWS * DMODEL * 2);
  short* ZX   = (short*)take((size_t)ROWS * DIN_PAD * 2);  // 36.7 MB
  short* XH   = (short*)take((size_t)ROWS * DINNER * 2);
  short* BMb  = (short*)take((size_t)ROWS * DSTATE * 2);
  short* CMb  = (short*)take((size_t)ROWS * DSTATE * 2);
  float* DTb  = (float*)take((size_t)ROWS * NHEADS * 4);
  short* Yb   = (short*)take((size_t)ROWS * DINNER * 2);
  short* YGB  = (short*)take((size_t)ROWS * DINNER * 2);   // 16 MB
  float* X2   = (float*)take((size_t)ROWS * DMODEL * 4);   // 16 MB (contiguous after YGB)
  short* X2NB = (short*)take((size_t)ROWS * DMODEL * 2);
  short* H1B  = (short*)take((size_t)ROWS * DMLP * 2);     // 32 MB

  // SSD scratch aliases (lifetimes disjoint):
  short* SC = H1B;          // write K1, read K2   | H1B written at mlp1 (later)
  short* HP = YGB;          // write K2, read K3   | spans YGB(16MB)+X2(16MB), both written later
  float* CS = (float*)X2NB; // write K1, read K2/K3| X2NB written at norm2 (later)
  // Split-K partials (2 x 4096x1024 f32 = 33.6MB) alias onto ZX (36.7MB, dead after gate_mnorm):
  float* PART = (float*)ZX;

  // weight converts
  cvt_kernel<<<4480, 256, 0, stream>>>(in_proj, W1B, DIN_PROJ, 10);
  cvt_kernel<<<2048, 256, 0, stream>>>(out_proj, W2B, DMODEL, 11);
  cvt_kernel<<<4096, 256, 0, stream>>>(mlp_w1, W3B, DMLP, 10);
  cvt_kernel<<<4096, 256, 0, stream>>>(mlp_w2, W4B, DMODEL, 12);

  // norm1 -> bf16
  rmsnorm_l2_kernel<<<ROWS, 256, 0, stream>>>(x, norm1_w, X1B);
  // in_proj GEMM -> ZX bf16 (1120 blocks, STG=2)
  gemm_bt_kernel<0,2><<<dim3(ROWS/128, DIN_PAD/128), 256, 0, stream>>>(X1B, W1B, nullptr, nullptr, ZX, DIN_PAD, DMODEL);
  // conv + dt (8-row blocks)
  conv_dt_kernel<<<ROWS/8, 256, 0, stream>>>(ZX, conv_w, conv_b, dt_bias, XH, BMb, CMb, DTb);
  // SSD chunked scan
  ssd_states_kernel<<<BATCH*NHEADS*NCHUNK, 256, 0, stream>>>(XH, BMb, DTb, A_log, CS, SC);
  ssd_prefix_kernel<<<BATCH*NHEADS*4, 256, 0, stream>>>(SC, CS, HP);
  ssd_out_kernel<<<BATCH*NHEADS*NCHUNK, 256, 0, stream>>>(XH, BMb, CMb, DTb, CS, HP, Dvec, Yb);
  // gate + mamba RMSNorm -> bf16 (last reader of ZX)
  gate_mnorm_kernel<<<ROWS, 256, 0, stream>>>(Yb, ZX, mnorm_w, YGB);
  // out_proj GEMM split-K=2 -> PART, then reduce(+x) -> X2
  gemm_bt_kernel<4,2><<<dim3(ROWS/128, DMODEL/128, 2), 256, 0, stream>>>(YGB, W2B, nullptr, nullptr, PART, DMODEL, DINNER);
  reduce_split2_kernel<false><<<ROWS*DMODEL/1024, 256, 0, stream>>>(PART, x, nullptr, X2);
  // norm2 -> bf16
  rmsnorm_l2_kernel<<<ROWS, 256, 0, stream>>>(X2, norm2_w, X2NB);
  // mlp1 GEMM + bias + exact gelu -> bf16 (1024 blocks, STG=2)
  gemm_bt_kernel<2,2><<<dim3(ROWS/128, DMLP/128), 256, 0, stream>>>(X2NB, W3B, mlp_b1, nullptr, H1B, DMLP, DMODEL);
  // mlp2 GEMM split-K=2 -> PART, then reduce(+bias+X2) -> d_out
  gemm_bt_kernel<4,2><<<dim3(ROWS/128, DMODEL/128, 2), 256, 0, stream>>>(H1B, W4B, nullptr, nullptr, PART, DMODEL, DMLP);
  reduce_split2_kernel<true><<<ROWS*DMODEL/1024, 256, 0, stream>>>(PART, X2, mlp_b2, outp);
}